// Round 1
// 1050.475 us; speedup vs baseline: 1.0343x; 1.0343x over previous
//
#include <hip/hip_runtime.h>
#include <hip/hip_bf16.h>

#define B_ 2
#define S_ 2048
#define D_ 4096
#define NH_ 32
#define NKV_ 8
#define HD_ 128
#define NREP_ 4

typedef unsigned short u16;
typedef __attribute__((ext_vector_type(8))) short short8;
typedef __attribute__((ext_vector_type(4))) float f32x4;

__device__ inline float bf2f(u16 u) {
    union { unsigned u; float f; } v; v.u = ((unsigned)u) << 16; return v.f;
}
__device__ inline u16 f2bf(float f) {
    union { float f; unsigned u; } v; v.f = f;
    unsigned r = v.u + 0x7fffu + ((v.u >> 16) & 1u);
    return (u16)(r >> 16);
}
__device__ inline unsigned pack_bf16(float a, float b) {
    return (unsigned)f2bf(a) | ((unsigned)f2bf(b) << 16);
}

// async global->LDS, 16 bytes/lane (m97-verified). LDS base wave-uniform.
__device__ inline void gl_lds16(const u16* g, u16* l) {
    __builtin_amdgcn_global_load_lds(
        (const __attribute__((address_space(1))) unsigned int*)g,
        (__attribute__((address_space(3))) unsigned int*)l, 16, 0, 0);
}

// ---------------- elementwise f32 -> bf16 ----------------------------------
__global__ __launch_bounds__(256) void conv_k(const float* __restrict__ in,
                                              u16* __restrict__ out) {
    size_t i = ((size_t)blockIdx.x * 256 + threadIdx.x) * 4;
    float4 v = *(const float4*)&in[i];
    u16 t[4] = {f2bf(v.x), f2bf(v.y), f2bf(v.z), f2bf(v.w)};
    *(uint2*)&out[i] = *(const uint2*)t;
}

// ---------------- transpose+convert: f32 in [R][C] -> bf16 out [C][R] ------
__global__ __launch_bounds__(256) void tconv_k(const float* __restrict__ in,
                                               u16* __restrict__ out,
                                               int R, int C) {
    __shared__ u16 tile[64][65];
    int bx = blockIdx.x * 64, by = blockIdx.y * 64;
    int tx = threadIdx.x, ty = threadIdx.y;
    for (int i = ty; i < 64; i += 4)
        tile[i][tx] = f2bf(in[(size_t)(by + i) * C + bx + tx]);
    __syncthreads();
    for (int i = ty; i < 64; i += 4)
        out[(size_t)(bx + i) * R + by + tx] = tile[tx][i];
}

// ---------------- transpose bf16: in [R][C] -> out [C][R] ------------------
__global__ __launch_bounds__(256) void transpose_k(const u16* __restrict__ in,
                                                   u16* __restrict__ out,
                                                   int R, int C) {
    __shared__ u16 tile[64][65];
    int bx = blockIdx.x * 64, by = blockIdx.y * 64;
    int tx = threadIdx.x, ty = threadIdx.y;
    for (int i = ty; i < 64; i += 4)
        tile[i][tx] = in[(size_t)(by + i) * C + bx + tx];
    __syncthreads();
    for (int i = ty; i < 64; i += 4)
        out[(size_t)(bx + i) * R + by + tx] = tile[tx][i];
}

// ---------------- GEMM (m97 structure): C[M][N] = A[M][K] * Bt[N][K]^T -----
template <int OUT_F32>
__global__ __launch_bounds__(256) void gemm_bt(const u16* __restrict__ A,
                                               const u16* __restrict__ Bt,
                                               void* __restrict__ Cv,
                                               int M, int N, int K) {
    __shared__ __align__(16) u16 As[128 * 32];   // [m][k] unpadded (DMA layout)
    __shared__ __align__(16) u16 Bs[128 * 32];   // [n][k]
    int tid = threadIdx.x;
    int w = tid >> 6, lane = tid & 63;
    int ln = lane & 15, qd = lane >> 4;
    int wr = w >> 1, wc = w & 1;
    int m0 = blockIdx.y * 128, n0 = blockIdx.x * 128;

    int srow = lane >> 2;
    int skk  = (lane & 3) * 8;
    const u16* Ag = A  + (size_t)(m0 + w * 32 + srow) * K + skk;
    const u16* Bg = Bt + (size_t)(n0 + w * 32 + srow) * K + skk;

    f32x4 acc[4][4];
#pragma unroll
    for (int i = 0; i < 4; ++i)
#pragma unroll
        for (int j = 0; j < 4; ++j)
            acc[i][j] = f32x4{0.f, 0.f, 0.f, 0.f};

    for (int k0 = 0; k0 < K; k0 += 32) {
#pragma unroll
        for (int t = 0; t < 2; ++t) {
            gl_lds16(Ag + (size_t)(t * 16) * K + k0, &As[(w * 32 + t * 16) * 32]);
            gl_lds16(Bg + (size_t)(t * 16) * K + k0, &Bs[(w * 32 + t * 16) * 32]);
        }
        __syncthreads();
        short8 af[4], bfr[4];
#pragma unroll
        for (int i = 0; i < 4; ++i)
            af[i] = *(const short8*)&As[(wr * 64 + i * 16 + ln) * 32 + qd * 8];
#pragma unroll
        for (int j = 0; j < 4; ++j)
            bfr[j] = *(const short8*)&Bs[(wc * 64 + j * 16 + ln) * 32 + qd * 8];
#pragma unroll
        for (int i = 0; i < 4; ++i)
#pragma unroll
            for (int j = 0; j < 4; ++j)
                acc[i][j] = __builtin_amdgcn_mfma_f32_16x16x32_bf16(af[i], bfr[j], acc[i][j], 0, 0, 0);
        __syncthreads();
    }
#pragma unroll
    for (int i = 0; i < 4; ++i)
#pragma unroll
        for (int j = 0; j < 4; ++j)
#pragma unroll
            for (int r = 0; r < 4; ++r) {
                int row = m0 + wr * 64 + i * 16 + qd * 4 + r;
                int col = n0 + wc * 64 + j * 16 + ln;
                if (OUT_F32)
                    ((float*)Cv)[(size_t)row * N + col] = acc[i][j][r];
                else
                    ((u16*)Cv)[(size_t)row * N + col] = f2bf(acc[i][j][r]);
            }
}

// ---------------- RoPE (in-place on bf16, optional scale fold) -------------
__global__ void rope_k(u16* __restrict__ buf, int nheads, float scale) {
    int total = B_ * S_ * nheads * (HD_ / 2);
    int i = blockIdx.x * blockDim.x + threadIdx.x;
    if (i >= total) return;
    int p = i & 63;
    int h = (i >> 6) % nheads;
    int row = i / (64 * nheads);
    int s = row & (S_ - 1);
    float freq = __expf(-(float)(2 * p) * (9.210340371976184f / 128.0f));
    float ang = (float)s * freq;
    float c, sn;
    sincosf(ang, &sn, &c);                // sincosf(x, sin*, cos*)
    size_t base = ((size_t)row * nheads + h) * HD_ + 2 * p;
    float x0 = bf2f(buf[base]), x1 = bf2f(buf[base + 1]);
    buf[base]     = f2bf((x0 * c - x1 * sn) * scale);
    buf[base + 1] = f2bf((x0 * sn + x1 * c) * scale);
}

// ---------------- flash attention (transposed-S form) ----------------------
// grid (S/256, NH, B), 512 threads (8 waves); each block processes TWO
// complementary q-tiles: qt = bx and qt = 15-bx, so per-block work is
// (2*bx+2) + (32-2*bx) = 34 key-tiles, CONSTANT -> perfect load balance
// (512 blocks = exactly 2/CU resident, no tail).
// Per pass: wave w owns q-rows q0+w*16..+15. S^T = K·Q^T (C/D: row=key,
// col=q=ln); softmax per-lane over 16 regs + 2 shfl_xor; P~^T B-frag built
// via 8 shfls/kstep; O^T = V^T·P~^T.
__global__ __launch_bounds__(512) void attn_k(const u16* __restrict__ Q,
                                              const u16* __restrict__ K,
                                              const u16* __restrict__ Vt,
                                              u16* __restrict__ AO) {
    __shared__ __align__(16) u16 Ks[2][64 * 136];    // [sk][d] pad->136
    __shared__ __align__(16) u16 Vts[2][128 * 72];   // [d][sk] pad->72

    int tid = threadIdx.x;
    int w = tid >> 6, lane = tid & 63;
    int ln = lane & 15, qd = lane >> 4;

    int h  = blockIdx.y;
    int b  = blockIdx.z;
    int g  = h >> 2;

    const u16* Kbase = K + (size_t)(b * S_) * (NKV_ * HD_) + g * HD_;
    const u16* Vtb   = Vt + ((size_t)(b * NKV_ + g)) * HD_ * S_;

    // staging map (per thread, per tile): Ks chunks c=tid,tid+512 (row=c>>4,
    // blk=c&15); Vts chunks c=tid,tid+512 (row=c>>3, blk=c&7)
    int kr0 = tid >> 4, kb0 = (tid & 15) * 8;
    int kr1 = (tid + 512) >> 4, kb1 = kb0;           // (tid+512)&15 == tid&15
    int vr0 = tid >> 3, vb0 = (tid & 7) * 8;
    int vr1 = (tid + 512) >> 3, vb1 = vb0;

    for (int pass = 0; pass < 2; ++pass) {
        int qt = pass ? (S_ / 128 - 1 - (int)blockIdx.x) : (int)blockIdx.x;
        int q0 = qt * 128;

        // Q B-frag: B[k=hd][n=q=ln]
        const u16* qptr = Q + ((size_t)(b * S_ + q0 + w * 16 + ln)) * (NH_ * HD_) + h * HD_;
        short8 bq[4];
#pragma unroll
        for (int kq = 0; kq < 4; ++kq)
            bq[kq] = *(const short8*)(qptr + kq * 32 + qd * 8);

        f32x4 ot[8];                      // O^T: d = db*16+qd*4+r, q = ln
#pragma unroll
        for (int db = 0; db < 8; ++db) ot[db] = f32x4{0.f, 0.f, 0.f, 0.f};
        float m_s = -1e30f, l_s = 0.f;

        int nk = 2 * qt + 2;
        int qg = q0 + w * 16 + ln;        // this lane's q row
        int qmaxw = q0 + w * 16 + 15;     // wave's max q

        // prologue: stage tile 0 into buf 0
        // (safe vs previous pass: its loop ended with __syncthreads())
        {
            int4 a0 = *(const int4*)(Kbase + (size_t)kr0 * (NKV_ * HD_) + kb0);
            int4 a1 = *(const int4*)(Kbase + (size_t)kr1 * (NKV_ * HD_) + kb1);
            int4 v0 = *(const int4*)(Vtb + (size_t)vr0 * S_ + vb0);
            int4 v1 = *(const int4*)(Vtb + (size_t)vr1 * S_ + vb1);
            *(int4*)&Ks[0][kr0 * 136 + kb0] = a0;
            *(int4*)&Ks[0][kr1 * 136 + kb1] = a1;
            *(int4*)&Vts[0][vr0 * 72 + vb0] = v0;
            *(int4*)&Vts[0][vr1 * 72 + vb1] = v1;
        }
        __syncthreads();

        for (int kt = 0; kt < nk; ++kt) {
            int bb = kt & 1;
            int k0 = kt * 64;
            bool pf = (kt + 1 < nk);
            int4 pa0, pa1, pv0, pv1;
            if (pf) {
                int k0n = k0 + 64;
                pa0 = *(const int4*)(Kbase + (size_t)(k0n + kr0) * (NKV_ * HD_) + kb0);
                pa1 = *(const int4*)(Kbase + (size_t)(k0n + kr1) * (NKV_ * HD_) + kb1);
                pv0 = *(const int4*)(Vtb + (size_t)vr0 * S_ + k0n + vb0);
                pv1 = *(const int4*)(Vtb + (size_t)vr1 * S_ + k0n + vb1);
            }

            if (k0 <= qmaxw) {            // wave has at least one unmasked key
                // S^T = K Q^T : A = K-frag (m=key), B = Q-frag (n=q)
                f32x4 st[4];
#pragma unroll
                for (int kb = 0; kb < 4; ++kb) st[kb] = f32x4{0.f, 0.f, 0.f, 0.f};
#pragma unroll
                for (int kb = 0; kb < 4; ++kb)
#pragma unroll
                    for (int kq = 0; kq < 4; ++kq) {
                        short8 ak = *(const short8*)&Ks[bb][(kb * 16 + ln) * 136 + kq * 32 + qd * 8];
                        st[kb] = __builtin_amdgcn_mfma_f32_16x16x32_bf16(ak, bq[kq], st[kb], 0, 0, 0);
                    }
                // causal mask + running max (key = k0 + kb*16 + qd*4 + r, q = qg)
                float mx = -1e30f;
#pragma unroll
                for (int kb = 0; kb < 4; ++kb)
#pragma unroll
                    for (int r = 0; r < 4; ++r) {
                        int kg = k0 + kb * 16 + qd * 4 + r;
                        if (kg > qg) st[kb][r] = -1e30f;
                        mx = fmaxf(mx, st[kb][r]);
                    }
                mx = fmaxf(mx, __shfl_xor(mx, 16, 64));
                mx = fmaxf(mx, __shfl_xor(mx, 32, 64));
                float mn = fmaxf(m_s, mx);
                float alpha = __expf(m_s - mn);
                m_s = mn;
                float rs = 0.f;
#pragma unroll
                for (int kb = 0; kb < 4; ++kb)
#pragma unroll
                    for (int r = 0; r < 4; ++r) {
                        float pv = __expf(st[kb][r] - mn);
                        st[kb][r] = pv;
                        rs += pv;
                    }
                rs += __shfl_xor(rs, 16, 64);
                rs += __shfl_xor(rs, 32, 64);
                l_s = l_s * alpha + rs;
#pragma unroll
                for (int db = 0; db < 8; ++db)
#pragma unroll
                    for (int r = 0; r < 4; ++r) ot[db][r] *= alpha;

                // pack P~ to bf16 pairs per keyblock
                unsigned pk[4][2];
#pragma unroll
                for (int kb = 0; kb < 4; ++kb) {
                    pk[kb][0] = pack_bf16(st[kb][0], st[kb][1]);
                    pk[kb][1] = pack_bf16(st[kb][2], st[kb][3]);
                }
                // O^T += V^T P~^T
                int sA = ((qd & 1) << 5) + ln;   // (2*(qd&1))*16 + ln
                int sB = sA + 16;
                bool hi = (qd & 2) != 0;
#pragma unroll
                for (int ks = 0; ks < 2; ++ks) {
                    unsigned t0a = (unsigned)__shfl((int)pk[2 * ks][0], sA, 64);
                    unsigned t0b = (unsigned)__shfl((int)pk[2 * ks][1], sA, 64);
                    unsigned t1a = (unsigned)__shfl((int)pk[2 * ks + 1][0], sA, 64);
                    unsigned t1b = (unsigned)__shfl((int)pk[2 * ks + 1][1], sA, 64);
                    unsigned t2a = (unsigned)__shfl((int)pk[2 * ks][0], sB, 64);
                    unsigned t2b = (unsigned)__shfl((int)pk[2 * ks][1], sB, 64);
                    unsigned t3a = (unsigned)__shfl((int)pk[2 * ks + 1][0], sB, 64);
                    unsigned t3b = (unsigned)__shfl((int)pk[2 * ks + 1][1], sB, 64);
                    union { unsigned u[4]; short8 s8; } bp;
                    bp.u[0] = hi ? t1a : t0a;
                    bp.u[1] = hi ? t1b : t0b;
                    bp.u[2] = hi ? t3a : t2a;
                    bp.u[3] = hi ? t3b : t2b;
#pragma unroll
                    for (int db = 0; db < 8; ++db) {
                        short8 av = *(const short8*)&Vts[bb][(db * 16 + ln) * 72 + ks * 32 + qd * 8];
                        ot[db] = __builtin_amdgcn_mfma_f32_16x16x32_bf16(av, bp.s8, ot[db], 0, 0, 0);
                    }
                }
            }

            if (pf) {
                int nb = bb ^ 1;
                *(int4*)&Ks[nb][kr0 * 136 + kb0] = pa0;
                *(int4*)&Ks[nb][kr1 * 136 + kb1] = pa1;
                *(int4*)&Vts[nb][vr0 * 72 + vb0] = pv0;
                *(int4*)&Vts[nb][vr1 * 72 + vb1] = pv1;
            }
            __syncthreads();
        }

        // epilogue: O[q][d] = O^T / l
        float invl = 1.0f / l_s;
        size_t orow = (size_t)(b * S_ + q0 + w * 16 + ln) * (NH_ * HD_) + h * HD_;
#pragma unroll
        for (int db = 0; db < 8; ++db) {
            u16 t[4];
#pragma unroll
            for (int r = 0; r < 4; ++r) t[r] = f2bf(ot[db][r] * invl);
            *(uint2*)&AO[orow + db * 16 + qd * 4] = *(const uint2*)t;
        }
    }
}

extern "C" void kernel_launch(void* const* d_in, const int* in_sizes, int n_in,
                              void* d_out, int out_size, void* d_ws, size_t ws_size,
                              hipStream_t stream) {
    const float* x  = (const float*)d_in[0];
    const float* wq = (const float*)d_in[1];
    const float* wk = (const float*)d_in[2];
    const float* wv = (const float*)d_in[3];
    const float* wo = (const float*)d_in[4];
    float* out = (float*)d_out;

    char* p = (char*)d_ws;
    auto alloc = [&](size_t nelem) { u16* r = (u16*)p; p += nelem * 2; return r; };
    u16* xb  = alloc(4096ull * 4096);   // aliased by woT after projections
    u16* wqT = alloc(4096ull * 4096);   // aliased by Vt after projections
    u16* wkT = alloc(1024ull * 4096);
    u16* wvT = alloc(1024ull * 4096);
    u16* Q   = alloc(4096ull * 4096);
    u16* Kb  = alloc(4096ull * 1024);
    u16* Vb  = alloc(4096ull * 1024);
    u16* AO  = alloc(4096ull * 4096);

    dim3 tblk(64, 4);
    conv_k<<<16384, 256, 0, stream>>>(x, xb);
    tconv_k<<<dim3(64, 64), tblk, 0, stream>>>(wq, wqT, 4096, 4096);
    tconv_k<<<dim3(16, 64), tblk, 0, stream>>>(wk, wkT, 4096, 1024);
    tconv_k<<<dim3(16, 64), tblk, 0, stream>>>(wv, wvT, 4096, 1024);

    gemm_bt<0><<<dim3(32, 32), 256, 0, stream>>>(xb, wqT, Q, 4096, 4096, 4096);
    gemm_bt<0><<<dim3(8, 32), 256, 0, stream>>>(xb, wkT, Kb, 4096, 1024, 4096);
    gemm_bt<0><<<dim3(8, 32), 256, 0, stream>>>(xb, wvT, Vb, 4096, 1024, 4096);

    u16* woT = xb;
    u16* Vt  = wqT;
    tconv_k<<<dim3(64, 64), tblk, 0, stream>>>(wo, woT, 4096, 4096);

    int totq = B_ * S_ * NH_ * (HD_ / 2);
    rope_k<<<(totq + 255) / 256, 256, 0, stream>>>(Q, NH_, 0.08838834764831845f);
    int totk = B_ * S_ * NKV_ * (HD_ / 2);
    rope_k<<<(totk + 255) / 256, 256, 0, stream>>>(Kb, NKV_, 1.0f);

    for (int b = 0; b < B_; ++b)
        transpose_k<<<dim3(16, 32), tblk, 0, stream>>>(
            Vb + (size_t)b * S_ * (NKV_ * HD_), Vt + (size_t)b * (NKV_ * HD_) * S_, S_, NKV_ * HD_);

    attn_k<<<dim3(S_ / 256, NH_, B_), 512, 0, stream>>>(Q, Kb, Vt, AO);

    gemm_bt<1><<<dim3(32, 32), 256, 0, stream>>>(AO, woT, out, 4096, 4096, 4096);
}

// Round 2
// 879.513 us; speedup vs baseline: 1.2354x; 1.1944x over previous
//
#include <hip/hip_runtime.h>
#include <hip/hip_bf16.h>

#define B_ 2
#define S_ 2048
#define D_ 4096
#define NH_ 32
#define NKV_ 8
#define HD_ 128
#define NREP_ 4

typedef unsigned short u16;
typedef __attribute__((ext_vector_type(8))) short short8;
typedef __attribute__((ext_vector_type(4))) float f32x4;

__device__ inline float bf2f(u16 u) {
    union { unsigned u; float f; } v; v.u = ((unsigned)u) << 16; return v.f;
}
__device__ inline u16 f2bf(float f) {
    union { float f; unsigned u; } v; v.f = f;
    unsigned r = v.u + 0x7fffu + ((v.u >> 16) & 1u);
    return (u16)(r >> 16);
}
__device__ inline unsigned pack_bf16(float a, float b) {
    return (unsigned)f2bf(a) | ((unsigned)f2bf(b) << 16);
}

// async global->LDS, 16 bytes/lane (m97-verified). LDS base wave-uniform.
__device__ inline void gl_lds16(const u16* g, u16* l) {
    __builtin_amdgcn_global_load_lds(
        (const __attribute__((address_space(1))) unsigned int*)g,
        (__attribute__((address_space(3))) unsigned int*)l, 16, 0, 0);
}

// ---------------- elementwise f32 -> bf16 ----------------------------------
__global__ __launch_bounds__(256) void conv_k(const float* __restrict__ in,
                                              u16* __restrict__ out) {
    size_t i = ((size_t)blockIdx.x * 256 + threadIdx.x) * 4;
    float4 v = *(const float4*)&in[i];
    u16 t[4] = {f2bf(v.x), f2bf(v.y), f2bf(v.z), f2bf(v.w)};
    *(uint2*)&out[i] = *(const uint2*)t;
}

// ---------------- transpose+convert: f32 in [R][C] -> bf16 out [C][R] ------
__global__ __launch_bounds__(256) void tconv_k(const float* __restrict__ in,
                                               u16* __restrict__ out,
                                               int R, int C) {
    __shared__ u16 tile[64][65];
    int bx = blockIdx.x * 64, by = blockIdx.y * 64;
    int tx = threadIdx.x, ty = threadIdx.y;
    for (int i = ty; i < 64; i += 4)
        tile[i][tx] = f2bf(in[(size_t)(by + i) * C + bx + tx]);
    __syncthreads();
    for (int i = ty; i < 64; i += 4)
        out[(size_t)(bx + i) * R + by + tx] = tile[tx][i];
}

// ---------------- transpose bf16: in [R][C] -> out [C][R] ------------------
__global__ __launch_bounds__(256) void transpose_k(const u16* __restrict__ in,
                                                   u16* __restrict__ out,
                                                   int R, int C) {
    __shared__ u16 tile[64][65];
    int bx = blockIdx.x * 64, by = blockIdx.y * 64;
    int tx = threadIdx.x, ty = threadIdx.y;
    for (int i = ty; i < 64; i += 4)
        tile[i][tx] = in[(size_t)(by + i) * C + bx + tx];
    __syncthreads();
    for (int i = ty; i < 64; i += 4)
        out[(size_t)(bx + i) * R + by + tx] = tile[tx][i];
}

// ---------------- GEMM (m97 structure, 128^2): for N=1024 projections ------
template <int OUT_F32>
__global__ __launch_bounds__(256) void gemm_bt(const u16* __restrict__ A,
                                               const u16* __restrict__ Bt,
                                               void* __restrict__ Cv,
                                               int M, int N, int K) {
    __shared__ __align__(16) u16 As[128 * 32];   // [m][k] unpadded (DMA layout)
    __shared__ __align__(16) u16 Bs[128 * 32];   // [n][k]
    int tid = threadIdx.x;
    int w = tid >> 6, lane = tid & 63;
    int ln = lane & 15, qd = lane >> 4;
    int wr = w >> 1, wc = w & 1;
    int m0 = blockIdx.y * 128, n0 = blockIdx.x * 128;

    int srow = lane >> 2;
    int skk  = (lane & 3) * 8;
    const u16* Ag = A  + (size_t)(m0 + w * 32 + srow) * K + skk;
    const u16* Bg = Bt + (size_t)(n0 + w * 32 + srow) * K + skk;

    f32x4 acc[4][4];
#pragma unroll
    for (int i = 0; i < 4; ++i)
#pragma unroll
        for (int j = 0; j < 4; ++j)
            acc[i][j] = f32x4{0.f, 0.f, 0.f, 0.f};

    for (int k0 = 0; k0 < K; k0 += 32) {
#pragma unroll
        for (int t = 0; t < 2; ++t) {
            gl_lds16(Ag + (size_t)(t * 16) * K + k0, &As[(w * 32 + t * 16) * 32]);
            gl_lds16(Bg + (size_t)(t * 16) * K + k0, &Bs[(w * 32 + t * 16) * 32]);
        }
        __syncthreads();
        short8 af[4], bfr[4];
#pragma unroll
        for (int i = 0; i < 4; ++i)
            af[i] = *(const short8*)&As[(wr * 64 + i * 16 + ln) * 32 + qd * 8];
#pragma unroll
        for (int j = 0; j < 4; ++j)
            bfr[j] = *(const short8*)&Bs[(wc * 64 + j * 16 + ln) * 32 + qd * 8];
#pragma unroll
        for (int i = 0; i < 4; ++i)
#pragma unroll
            for (int j = 0; j < 4; ++j)
                acc[i][j] = __builtin_amdgcn_mfma_f32_16x16x32_bf16(af[i], bfr[j], acc[i][j], 0, 0, 0);
        __syncthreads();
    }
#pragma unroll
    for (int i = 0; i < 4; ++i)
#pragma unroll
        for (int j = 0; j < 4; ++j)
#pragma unroll
            for (int r = 0; r < 4; ++r) {
                int row = m0 + wr * 64 + i * 16 + qd * 4 + r;
                int col = n0 + wc * 64 + j * 16 + ln;
                if (OUT_F32)
                    ((float*)Cv)[(size_t)row * N + col] = acc[i][j][r];
                else
                    ((u16*)Cv)[(size_t)row * N + col] = f2bf(acc[i][j][r]);
            }
}

// ---------------- GEMM 256^2 8-phase (m201 template, T2+T3+T4+T5) ----------
// BM=BN=256, BK=64, 512 thr (8 waves, 2Mx4N), per-wave out 128x64.
// LDS 128KB: A[2][2half][128][64] + B same, st_16x32 swizzle
// (byte ^= ((byte>>9)&1)<<5) applied as inverse-swizzled GLOBAL source for
// global_load_lds (linear dest) + swizzled ds_read (rule #21).
// Phase p reads A-frags mi{2p,2p+1} (+ all B-frags at p0); prefetch slots:
// p0: A(t+1)lo  p1: A(t+1)hi  p2: B(t+2)lo  p3: B(t+2)hi  (B of cur buf is
// free after p0, A of other buf free after prev tile's p3 -> race-free).
// vmcnt(4) at p3 drains tile t+1 fully, leaves B(t+2)'s 4 loads in flight.

// read fragment: row in [0,256), colb = byte col in [0,128)
__device__ inline short8 lds_frag(const u16* base, int row, int colb) {
    int lin = ((row & 127) << 7) + colb;
    int off = ((row >> 7) << 14) + (lin ^ (((lin >> 9) & 1) << 5));
    return *(const short8*)((const char*)base + off);
}

// stage one 128-row x 64-col half-tile: 2 gl_lds per wave, pre-swizzled src
__device__ inline void stage_half(const u16* g, int row0, int ldK, int k0,
                                  u16* ldsHalf, int w, int lane) {
#pragma unroll
    for (int j = 0; j < 2; ++j) {
        int Lb = (w << 11) + (j << 10) + (lane << 4);    // linear dest byte
        int src = Lb ^ (((Lb >> 9) & 1) << 5);           // inverse-swizzled src
        const u16* gp = g + (size_t)(row0 + (src >> 7)) * ldK + k0 + ((src & 127) >> 1);
        gl_lds16(gp, ldsHalf + (((w << 11) + (j << 10)) >> 1));
    }
}

#define PH_MFMA(MB)                                                           \
    asm volatile("s_waitcnt lgkmcnt(0)" ::: "memory");                        \
    __builtin_amdgcn_sched_barrier(0);                                        \
    __builtin_amdgcn_s_setprio(1);                                            \
    _Pragma("unroll") for (int mi = 0; mi < 2; ++mi)                          \
      _Pragma("unroll") for (int ni = 0; ni < 4; ++ni)                        \
        _Pragma("unroll") for (int kk = 0; kk < 2; ++kk)                      \
          acc[(MB) + mi][ni] = __builtin_amdgcn_mfma_f32_16x16x32_bf16(       \
              af[mi][kk], bfr[ni][kk], acc[(MB) + mi][ni], 0, 0, 0);          \
    __builtin_amdgcn_s_setprio(0);                                            \
    __builtin_amdgcn_s_barrier();

#define TILE_BODY(T, CURA, CURB, OTHA)                                        \
  {                                                                           \
    const int t_ = (T);                                                       \
    const bool p1_ = (t_ + 1 < nt), p2_ = (t_ + 2 < nt);                      \
    short8 bfr[4][2], af[2][2];                                               \
    /* phase 0: read B all + A mi0-1; stage A(t+1) half0 */                   \
    _Pragma("unroll") for (int ni = 0; ni < 4; ++ni)                          \
      _Pragma("unroll") for (int kk = 0; kk < 2; ++kk)                        \
        bfr[ni][kk] = lds_frag(CURB, wn * 64 + ni * 16 + ln, kk * 64 + qd * 16); \
    _Pragma("unroll") for (int mi = 0; mi < 2; ++mi)                          \
      _Pragma("unroll") for (int kk = 0; kk < 2; ++kk)                        \
        af[mi][kk] = lds_frag(CURA, wm * 128 + mi * 16 + ln, kk * 64 + qd * 16); \
    if (p1_) stage_half(Ag, 0, K, (t_ + 1) << 6, OTHA, w, lane);              \
    asm volatile("s_waitcnt lgkmcnt(8)" ::: "memory");                        \
    __builtin_amdgcn_s_barrier();                                             \
    PH_MFMA(0)                                                                \
    /* phase 1: A mi2-3; stage A(t+1) half1 */                                \
    _Pragma("unroll") for (int mi = 0; mi < 2; ++mi)                          \
      _Pragma("unroll") for (int kk = 0; kk < 2; ++kk)                        \
        af[mi][kk] = lds_frag(CURA, wm * 128 + (mi + 2) * 16 + ln, kk * 64 + qd * 16); \
    if (p1_) stage_half(Ag, 128, K, (t_ + 1) << 6, OTHA + 8192, w, lane);     \
    __builtin_amdgcn_s_barrier();                                             \
    PH_MFMA(2)                                                                \
    /* phase 2: A mi4-5; stage B(t+2) half0 */                                \
    _Pragma("unroll") for (int mi = 0; mi < 2; ++mi)                          \
      _Pragma("unroll") for (int kk = 0; kk < 2; ++kk)                        \
        af[mi][kk] = lds_frag(CURA, wm * 128 + (mi + 4) * 16 + ln, kk * 64 + qd * 16); \
    if (p2_) stage_half(Bg, 0, K, (t_ + 2) << 6, CURB, w, lane);              \
    __builtin_amdgcn_s_barrier();                                             \
    PH_MFMA(4)                                                                \
    /* phase 3: A mi6-7; stage B(t+2) half1; counted vmcnt */                 \
    _Pragma("unroll") for (int mi = 0; mi < 2; ++mi)                          \
      _Pragma("unroll") for (int kk = 0; kk < 2; ++kk)                        \
        af[mi][kk] = lds_frag(CURA, wm * 128 + (mi + 6) * 16 + ln, kk * 64 + qd * 16); \
    if (p2_) {                                                                \
        stage_half(Bg, 128, K, (t_ + 2) << 6, CURB + 8192, w, lane);          \
        asm volatile("s_waitcnt vmcnt(4)" ::: "memory");                      \
    } else if (p1_) {                                                         \
        asm volatile("s_waitcnt vmcnt(0)" ::: "memory");                      \
    }                                                                         \
    __builtin_amdgcn_s_barrier();                                             \
    PH_MFMA(6)                                                                \
  }

template <int OUT_F32>
__global__ __launch_bounds__(512, 1) void gemm256(const u16* __restrict__ A,
                                                  const u16* __restrict__ Bt,
                                                  void* __restrict__ Cv,
                                                  int M, int N, int K) {
    __shared__ __align__(16) u16 As[2][16384];   // [buf][half*8192]
    __shared__ __align__(16) u16 Bs[2][16384];

    int tid = threadIdx.x;
    int w = tid >> 6, lane = tid & 63;
    int ln = lane & 15, qd = lane >> 4;
    int wm = w >> 2, wn = w & 3;

    int nbx = N >> 8;
    int cpx = gridDim.x >> 3;                     // grid % 8 == 0 (bijective)
    int bid = blockIdx.x;
    int swz = (bid & 7) * cpx + (bid >> 3);
    int m0 = (swz / nbx) << 8;
    int n0 = (swz % nbx) << 8;

    const u16* Ag = A + (size_t)m0 * K;
    const u16* Bg = Bt + (size_t)n0 * K;
    int nt = K >> 6;

    f32x4 acc[8][4];
#pragma unroll
    for (int i = 0; i < 8; ++i)
#pragma unroll
        for (int j = 0; j < 4; ++j) acc[i][j] = f32x4{0.f, 0.f, 0.f, 0.f};

    u16* A0 = &As[0][0]; u16* A1v = &As[1][0];
    u16* B0 = &Bs[0][0]; u16* B1v = &Bs[1][0];

    // prologue: tile0 (4 halves) + B(1) (2 halves); drain tile0, keep B(1) in flight
    stage_half(Ag, 0,   K, 0,  A0,         w, lane);
    stage_half(Ag, 128, K, 0,  A0 + 8192,  w, lane);
    stage_half(Bg, 0,   K, 0,  B0,         w, lane);
    stage_half(Bg, 128, K, 0,  B0 + 8192,  w, lane);
    stage_half(Bg, 0,   K, 64, B1v,        w, lane);
    stage_half(Bg, 128, K, 64, B1v + 8192, w, lane);
    asm volatile("s_waitcnt vmcnt(4)" ::: "memory");
    __builtin_amdgcn_s_barrier();

    for (int tt = 0; tt < nt; tt += 2) {
        TILE_BODY(tt,     A0,  B0,  A1v)
        TILE_BODY(tt + 1, A1v, B1v, A0)
    }

#pragma unroll
    for (int mi = 0; mi < 8; ++mi)
#pragma unroll
        for (int ni = 0; ni < 4; ++ni)
#pragma unroll
            for (int r = 0; r < 4; ++r) {
                int row = m0 + wm * 128 + mi * 16 + qd * 4 + r;
                int col = n0 + wn * 64 + ni * 16 + ln;
                if (OUT_F32)
                    ((float*)Cv)[(size_t)row * N + col] = acc[mi][ni][r];
                else
                    ((u16*)Cv)[(size_t)row * N + col] = f2bf(acc[mi][ni][r]);
            }
}

// ---------------- RoPE (in-place on bf16, optional scale fold) -------------
__global__ void rope_k(u16* __restrict__ buf, int nheads, float scale) {
    int total = B_ * S_ * nheads * (HD_ / 2);
    int i = blockIdx.x * blockDim.x + threadIdx.x;
    if (i >= total) return;
    int p = i & 63;
    int h = (i >> 6) % nheads;
    int row = i / (64 * nheads);
    int s = row & (S_ - 1);
    float freq = __expf(-(float)(2 * p) * (9.210340371976184f / 128.0f));
    float ang = (float)s * freq;
    float c, sn;
    sincosf(ang, &sn, &c);                // sincosf(x, sin*, cos*)
    size_t base = ((size_t)row * nheads + h) * HD_ + 2 * p;
    float x0 = bf2f(buf[base]), x1 = bf2f(buf[base + 1]);
    buf[base]     = f2bf((x0 * c - x1 * sn) * scale);
    buf[base + 1] = f2bf((x0 * sn + x1 * c) * scale);
}

// ---------------- flash attention (transposed-S form) ----------------------
// grid (S/256, NH, B), 512 threads (8 waves); each block processes TWO
// complementary q-tiles: qt = bx and qt = 15-bx -> constant 34 key-tiles.
__global__ __launch_bounds__(512) void attn_k(const u16* __restrict__ Q,
                                              const u16* __restrict__ K,
                                              const u16* __restrict__ Vt,
                                              u16* __restrict__ AO) {
    __shared__ __align__(16) u16 Ks[2][64 * 136];    // [sk][d] pad->136
    __shared__ __align__(16) u16 Vts[2][128 * 72];   // [d][sk] pad->72

    int tid = threadIdx.x;
    int w = tid >> 6, lane = tid & 63;
    int ln = lane & 15, qd = lane >> 4;

    int h  = blockIdx.y;
    int b  = blockIdx.z;
    int g  = h >> 2;

    const u16* Kbase = K + (size_t)(b * S_) * (NKV_ * HD_) + g * HD_;
    const u16* Vtb   = Vt + ((size_t)(b * NKV_ + g)) * HD_ * S_;

    int kr0 = tid >> 4, kb0 = (tid & 15) * 8;
    int kr1 = (tid + 512) >> 4, kb1 = kb0;
    int vr0 = tid >> 3, vb0 = (tid & 7) * 8;
    int vr1 = (tid + 512) >> 3, vb1 = vb0;

    for (int pass = 0; pass < 2; ++pass) {
        int qt = pass ? (S_ / 128 - 1 - (int)blockIdx.x) : (int)blockIdx.x;
        int q0 = qt * 128;

        const u16* qptr = Q + ((size_t)(b * S_ + q0 + w * 16 + ln)) * (NH_ * HD_) + h * HD_;
        short8 bq[4];
#pragma unroll
        for (int kq = 0; kq < 4; ++kq)
            bq[kq] = *(const short8*)(qptr + kq * 32 + qd * 8);

        f32x4 ot[8];
#pragma unroll
        for (int db = 0; db < 8; ++db) ot[db] = f32x4{0.f, 0.f, 0.f, 0.f};
        float m_s = -1e30f, l_s = 0.f;

        int nk = 2 * qt + 2;
        int qg = q0 + w * 16 + ln;
        int qmaxw = q0 + w * 16 + 15;

        {
            int4 a0 = *(const int4*)(Kbase + (size_t)kr0 * (NKV_ * HD_) + kb0);
            int4 a1 = *(const int4*)(Kbase + (size_t)kr1 * (NKV_ * HD_) + kb1);
            int4 v0 = *(const int4*)(Vtb + (size_t)vr0 * S_ + vb0);
            int4 v1 = *(const int4*)(Vtb + (size_t)vr1 * S_ + vb1);
            *(int4*)&Ks[0][kr0 * 136 + kb0] = a0;
            *(int4*)&Ks[0][kr1 * 136 + kb1] = a1;
            *(int4*)&Vts[0][vr0 * 72 + vb0] = v0;
            *(int4*)&Vts[0][vr1 * 72 + vb1] = v1;
        }
        __syncthreads();

        for (int kt = 0; kt < nk; ++kt) {
            int bb = kt & 1;
            int k0 = kt * 64;
            bool pf = (kt + 1 < nk);
            int4 pa0, pa1, pv0, pv1;
            if (pf) {
                int k0n = k0 + 64;
                pa0 = *(const int4*)(Kbase + (size_t)(k0n + kr0) * (NKV_ * HD_) + kb0);
                pa1 = *(const int4*)(Kbase + (size_t)(k0n + kr1) * (NKV_ * HD_) + kb1);
                pv0 = *(const int4*)(Vtb + (size_t)vr0 * S_ + k0n + vb0);
                pv1 = *(const int4*)(Vtb + (size_t)vr1 * S_ + k0n + vb1);
            }

            if (k0 <= qmaxw) {
                f32x4 st[4];
#pragma unroll
                for (int kb = 0; kb < 4; ++kb) st[kb] = f32x4{0.f, 0.f, 0.f, 0.f};
#pragma unroll
                for (int kb = 0; kb < 4; ++kb)
#pragma unroll
                    for (int kq = 0; kq < 4; ++kq) {
                        short8 ak = *(const short8*)&Ks[bb][(kb * 16 + ln) * 136 + kq * 32 + qd * 8];
                        st[kb] = __builtin_amdgcn_mfma_f32_16x16x32_bf16(ak, bq[kq], st[kb], 0, 0, 0);
                    }
                float mx = -1e30f;
#pragma unroll
                for (int kb = 0; kb < 4; ++kb)
#pragma unroll
                    for (int r = 0; r < 4; ++r) {
                        int kg = k0 + kb * 16 + qd * 4 + r;
                        if (kg > qg) st[kb][r] = -1e30f;
                        mx = fmaxf(mx, st[kb][r]);
                    }
                mx = fmaxf(mx, __shfl_xor(mx, 16, 64));
                mx = fmaxf(mx, __shfl_xor(mx, 32, 64));
                float mn = fmaxf(m_s, mx);
                float alpha = __expf(m_s - mn);
                m_s = mn;
                float rs = 0.f;
#pragma unroll
                for (int kb = 0; kb < 4; ++kb)
#pragma unroll
                    for (int r = 0; r < 4; ++r) {
                        float pv = __expf(st[kb][r] - mn);
                        st[kb][r] = pv;
                        rs += pv;
                    }
                rs += __shfl_xor(rs, 16, 64);
                rs += __shfl_xor(rs, 32, 64);
                l_s = l_s * alpha + rs;
#pragma unroll
                for (int db = 0; db < 8; ++db)
#pragma unroll
                    for (int r = 0; r < 4; ++r) ot[db][r] *= alpha;

                unsigned pk[4][2];
#pragma unroll
                for (int kb = 0; kb < 4; ++kb) {
                    pk[kb][0] = pack_bf16(st[kb][0], st[kb][1]);
                    pk[kb][1] = pack_bf16(st[kb][2], st[kb][3]);
                }
                int sA = ((qd & 1) << 5) + ln;
                int sB = sA + 16;
                bool hi = (qd & 2) != 0;
#pragma unroll
                for (int ks = 0; ks < 2; ++ks) {
                    unsigned t0a = (unsigned)__shfl((int)pk[2 * ks][0], sA, 64);
                    unsigned t0b = (unsigned)__shfl((int)pk[2 * ks][1], sA, 64);
                    unsigned t1a = (unsigned)__shfl((int)pk[2 * ks + 1][0], sA, 64);
                    unsigned t1b = (unsigned)__shfl((int)pk[2 * ks + 1][1], sA, 64);
                    unsigned t2a = (unsigned)__shfl((int)pk[2 * ks][0], sB, 64);
                    unsigned t2b = (unsigned)__shfl((int)pk[2 * ks][1], sB, 64);
                    unsigned t3a = (unsigned)__shfl((int)pk[2 * ks + 1][0], sB, 64);
                    unsigned t3b = (unsigned)__shfl((int)pk[2 * ks + 1][1], sB, 64);
                    union { unsigned u[4]; short8 s8; } bp;
                    bp.u[0] = hi ? t1a : t0a;
                    bp.u[1] = hi ? t1b : t0b;
                    bp.u[2] = hi ? t3a : t2a;
                    bp.u[3] = hi ? t3b : t2b;
#pragma unroll
                    for (int db = 0; db < 8; ++db) {
                        short8 av = *(const short8*)&Vts[bb][(db * 16 + ln) * 72 + ks * 32 + qd * 8];
                        ot[db] = __builtin_amdgcn_mfma_f32_16x16x32_bf16(av, bp.s8, ot[db], 0, 0, 0);
                    }
                }
            }

            if (pf) {
                int nb = bb ^ 1;
                *(int4*)&Ks[nb][kr0 * 136 + kb0] = pa0;
                *(int4*)&Ks[nb][kr1 * 136 + kb1] = pa1;
                *(int4*)&Vts[nb][vr0 * 72 + vb0] = pv0;
                *(int4*)&Vts[nb][vr1 * 72 + vb1] = pv1;
            }
            __syncthreads();
        }

        float invl = 1.0f / l_s;
        size_t orow = (size_t)(b * S_ + q0 + w * 16 + ln) * (NH_ * HD_) + h * HD_;
#pragma unroll
        for (int db = 0; db < 8; ++db) {
            u16 t[4];
#pragma unroll
            for (int r = 0; r < 4; ++r) t[r] = f2bf(ot[db][r] * invl);
            *(uint2*)&AO[orow + db * 16 + qd * 4] = *(const uint2*)t;
        }
    }
}

extern "C" void kernel_launch(void* const* d_in, const int* in_sizes, int n_in,
                              void* d_out, int out_size, void* d_ws, size_t ws_size,
                              hipStream_t stream) {
    const float* x  = (const float*)d_in[0];
    const float* wq = (const float*)d_in[1];
    const float* wk = (const float*)d_in[2];
    const float* wv = (const float*)d_in[3];
    const float* wo = (const float*)d_in[4];
    float* out = (float*)d_out;

    char* p = (char*)d_ws;
    auto alloc = [&](size_t nelem) { u16* r = (u16*)p; p += nelem * 2; return r; };
    u16* xb  = alloc(4096ull * 4096);   // aliased by woT after projections
    u16* wqT = alloc(4096ull * 4096);   // aliased by Vt after projections
    u16* wkT = alloc(1024ull * 4096);
    u16* wvT = alloc(1024ull * 4096);
    u16* Q   = alloc(4096ull * 4096);
    u16* Kb  = alloc(4096ull * 1024);
    u16* Vb  = alloc(4096ull * 1024);
    u16* AO  = alloc(4096ull * 4096);

    dim3 tblk(64, 4);
    conv_k<<<16384, 256, 0, stream>>>(x, xb);
    tconv_k<<<dim3(64, 64), tblk, 0, stream>>>(wq, wqT, 4096, 4096);
    tconv_k<<<dim3(16, 64), tblk, 0, stream>>>(wk, wkT, 4096, 1024);
    tconv_k<<<dim3(16, 64), tblk, 0, stream>>>(wv, wvT, 4096, 1024);

    gemm256<0><<<256, 512, 0, stream>>>(xb, wqT, Q, 4096, 4096, 4096);
    gemm_bt<0><<<dim3(8, 32), 256, 0, stream>>>(xb, wkT, Kb, 4096, 1024, 4096);
    gemm_bt<0><<<dim3(8, 32), 256, 0, stream>>>(xb, wvT, Vb, 4096, 1024, 4096);

    u16* woT = xb;
    u16* Vt  = wqT;
    tconv_k<<<dim3(64, 64), tblk, 0, stream>>>(wo, woT, 4096, 4096);

    int totq = B_ * S_ * NH_ * (HD_ / 2);
    rope_k<<<(totq + 255) / 256, 256, 0, stream>>>(Q, NH_, 0.08838834764831845f);
    int totk = B_ * S_ * NKV_ * (HD_ / 2);
    rope_k<<<(totk + 255) / 256, 256, 0, stream>>>(Kb, NKV_, 1.0f);

    for (int b = 0; b < B_; ++b)
        transpose_k<<<dim3(16, 32), tblk, 0, stream>>>(
            Vb + (size_t)b * S_ * (NKV_ * HD_), Vt + (size_t)b * (NKV_ * HD_) * S_, S_, NKV_ * HD_);

    attn_k<<<dim3(S_ / 256, NH_, B_), 512, 0, stream>>>(Q, Kb, Vt, AO);

    gemm256<1><<<256, 512, 0, stream>>>(AO, woT, out, 4096, 4096, 4096);
}

// Round 3
// 756.230 us; speedup vs baseline: 1.4368x; 1.1630x over previous
//
#include <hip/hip_runtime.h>
#include <hip/hip_bf16.h>

#define B_ 2
#define S_ 2048
#define D_ 4096
#define NH_ 32
#define NKV_ 8
#define HD_ 128
#define NREP_ 4

typedef unsigned short u16;
typedef __attribute__((ext_vector_type(8))) short short8;
typedef __attribute__((ext_vector_type(4))) float f32x4;

__device__ inline float bf2f(u16 u) {
    union { unsigned u; float f; } v; v.u = ((unsigned)u) << 16; return v.f;
}
__device__ inline u16 f2bf(float f) {
    union { float f; unsigned u; } v; v.f = f;
    unsigned r = v.u + 0x7fffu + ((v.u >> 16) & 1u);
    return (u16)(r >> 16);
}
// HW packed f32x2 -> bf16x2 (RNE), one instr (T12 primitive)
__device__ inline unsigned cvt_pk(float lo, float hi) {
    unsigned r;
    asm("v_cvt_pk_bf16_f32 %0, %1, %2" : "=v"(r) : "v"(lo), "v"(hi));
    return r;
}
// v_exp_f32 = 2^x
__device__ inline float exp2_fast(float x) {
    float r;
    asm("v_exp_f32 %0, %1" : "=v"(r) : "v"(x));
    return r;
}

// async global->LDS, 16 bytes/lane (m97-verified). LDS base wave-uniform.
__device__ inline void gl_lds16(const u16* g, u16* l) {
    __builtin_amdgcn_global_load_lds(
        (const __attribute__((address_space(1))) unsigned int*)g,
        (__attribute__((address_space(3))) unsigned int*)l, 16, 0, 0);
}

// ---------------- elementwise f32 -> bf16 ----------------------------------
__global__ __launch_bounds__(256) void conv_k(const float* __restrict__ in,
                                              u16* __restrict__ out) {
    size_t i = ((size_t)blockIdx.x * 256 + threadIdx.x) * 4;
    float4 v = *(const float4*)&in[i];
    uint2 t;
    t.x = cvt_pk(v.x, v.y);
    t.y = cvt_pk(v.z, v.w);
    *(uint2*)&out[i] = t;
}

// ---------------- transpose+convert: f32 in [R][C] -> bf16 out [C][R] ------
__global__ __launch_bounds__(256) void tconv_k(const float* __restrict__ in,
                                               u16* __restrict__ out,
                                               int R, int C) {
    __shared__ u16 tile[64][65];
    int bx = blockIdx.x * 64, by = blockIdx.y * 64;
    int tx = threadIdx.x, ty = threadIdx.y;
    for (int i = ty; i < 64; i += 4)
        tile[i][tx] = f2bf(in[(size_t)(by + i) * C + bx + tx]);
    __syncthreads();
    for (int i = ty; i < 64; i += 4)
        out[(size_t)(bx + i) * R + by + tx] = tile[tx][i];
}

// z-batched variant: z=0 -> in0/out0, z=1 -> in1/out1
__global__ __launch_bounds__(256) void tconv2_k(const float* __restrict__ in0,
                                                const float* __restrict__ in1,
                                                u16* __restrict__ out0,
                                                u16* __restrict__ out1,
                                                int R, int C) {
    __shared__ u16 tile[64][65];
    const float* in = blockIdx.z ? in1 : in0;
    u16* out = blockIdx.z ? out1 : out0;
    int bx = blockIdx.x * 64, by = blockIdx.y * 64;
    int tx = threadIdx.x, ty = threadIdx.y;
    for (int i = ty; i < 64; i += 4)
        tile[i][tx] = f2bf(in[(size_t)(by + i) * C + bx + tx]);
    __syncthreads();
    for (int i = ty; i < 64; i += 4)
        out[(size_t)(bx + i) * R + by + tx] = tile[tx][i];
}

// ---------------- transpose bf16 (z-batched): in [R][C] -> out [C][R] ------
__global__ __launch_bounds__(256) void transpose_k(const u16* __restrict__ in,
                                                   u16* __restrict__ out,
                                                   int R, int C) {
    __shared__ u16 tile[64][65];
    const u16* ib = in + (size_t)blockIdx.z * R * C;
    u16* ob = out + (size_t)blockIdx.z * R * C;
    int bx = blockIdx.x * 64, by = blockIdx.y * 64;
    int tx = threadIdx.x, ty = threadIdx.y;
    for (int i = ty; i < 64; i += 4)
        tile[i][tx] = ib[(size_t)(by + i) * C + bx + tx];
    __syncthreads();
    for (int i = ty; i < 64; i += 4)
        ob[(size_t)(bx + i) * R + by + tx] = tile[tx][i];
}

// ---------------- merged K+V projection GEMM (m97 structure) ---------------
// Bt = wkT(1024 rows) || wvT(1024 rows), contiguous. N=2048.
// Output: cols 0-1023 -> Kout, 1024-2047 -> Vout (both row stride 1024).
__global__ __launch_bounds__(256) void gemm_kv(const u16* __restrict__ A,
                                               const u16* __restrict__ Bt,
                                               u16* __restrict__ Kout,
                                               u16* __restrict__ Vout,
                                               int M, int K) {
    __shared__ __align__(16) u16 As[128 * 32];
    __shared__ __align__(16) u16 Bs[128 * 32];
    int tid = threadIdx.x;
    int w = tid >> 6, lane = tid & 63;
    int ln = lane & 15, qd = lane >> 4;
    int wr = w >> 1, wc = w & 1;
    int m0 = blockIdx.y * 128, n0 = blockIdx.x * 128;

    int srow = lane >> 2;
    int skk  = (lane & 3) * 8;
    const u16* Ag = A  + (size_t)(m0 + w * 32 + srow) * K + skk;
    const u16* Bg = Bt + (size_t)(n0 + w * 32 + srow) * K + skk;

    f32x4 acc[4][4];
#pragma unroll
    for (int i = 0; i < 4; ++i)
#pragma unroll
        for (int j = 0; j < 4; ++j)
            acc[i][j] = f32x4{0.f, 0.f, 0.f, 0.f};

    for (int k0 = 0; k0 < K; k0 += 32) {
#pragma unroll
        for (int t = 0; t < 2; ++t) {
            gl_lds16(Ag + (size_t)(t * 16) * K + k0, &As[(w * 32 + t * 16) * 32]);
            gl_lds16(Bg + (size_t)(t * 16) * K + k0, &Bs[(w * 32 + t * 16) * 32]);
        }
        __syncthreads();
        short8 af[4], bfr[4];
#pragma unroll
        for (int i = 0; i < 4; ++i)
            af[i] = *(const short8*)&As[(wr * 64 + i * 16 + ln) * 32 + qd * 8];
#pragma unroll
        for (int j = 0; j < 4; ++j)
            bfr[j] = *(const short8*)&Bs[(wc * 64 + j * 16 + ln) * 32 + qd * 8];
#pragma unroll
        for (int i = 0; i < 4; ++i)
#pragma unroll
            for (int j = 0; j < 4; ++j)
                acc[i][j] = __builtin_amdgcn_mfma_f32_16x16x32_bf16(af[i], bfr[j], acc[i][j], 0, 0, 0);
        __syncthreads();
    }
    u16* dst = (n0 < 1024) ? Kout : Vout;
    int nb = (n0 < 1024) ? n0 : (n0 - 1024);
#pragma unroll
    for (int i = 0; i < 4; ++i)
#pragma unroll
        for (int j = 0; j < 4; ++j)
#pragma unroll
            for (int r = 0; r < 4; ++r) {
                int row = m0 + wr * 64 + i * 16 + qd * 4 + r;
                int col = nb + wc * 64 + j * 16 + ln;
                dst[(size_t)row * 1024 + col] = f2bf(acc[i][j][r]);
            }
}

// ---------------- GEMM 256^2 8-phase (m201 template, T2+T3+T4+T5) ----------
// (unchanged from round 2 — verified)
__device__ inline short8 lds_frag(const u16* base, int row, int colb) {
    int lin = ((row & 127) << 7) + colb;
    int off = ((row >> 7) << 14) + (lin ^ (((lin >> 9) & 1) << 5));
    return *(const short8*)((const char*)base + off);
}

__device__ inline void stage_half(const u16* g, int row0, int ldK, int k0,
                                  u16* ldsHalf, int w, int lane) {
#pragma unroll
    for (int j = 0; j < 2; ++j) {
        int Lb = (w << 11) + (j << 10) + (lane << 4);    // linear dest byte
        int src = Lb ^ (((Lb >> 9) & 1) << 5);           // inverse-swizzled src
        const u16* gp = g + (size_t)(row0 + (src >> 7)) * ldK + k0 + ((src & 127) >> 1);
        gl_lds16(gp, ldsHalf + (((w << 11) + (j << 10)) >> 1));
    }
}

#define PH_MFMA(MB)                                                           \
    asm volatile("s_waitcnt lgkmcnt(0)" ::: "memory");                        \
    __builtin_amdgcn_sched_barrier(0);                                        \
    __builtin_amdgcn_s_setprio(1);                                            \
    _Pragma("unroll") for (int mi = 0; mi < 2; ++mi)                          \
      _Pragma("unroll") for (int ni = 0; ni < 4; ++ni)                        \
        _Pragma("unroll") for (int kk = 0; kk < 2; ++kk)                      \
          acc[(MB) + mi][ni] = __builtin_amdgcn_mfma_f32_16x16x32_bf16(       \
              af[mi][kk], bfr[ni][kk], acc[(MB) + mi][ni], 0, 0, 0);          \
    __builtin_amdgcn_s_setprio(0);                                            \
    __builtin_amdgcn_s_barrier();

#define TILE_BODY(T, CURA, CURB, OTHA)                                        \
  {                                                                           \
    const int t_ = (T);                                                       \
    const bool p1_ = (t_ + 1 < nt), p2_ = (t_ + 2 < nt);                      \
    short8 bfr[4][2], af[2][2];                                               \
    _Pragma("unroll") for (int ni = 0; ni < 4; ++ni)                          \
      _Pragma("unroll") for (int kk = 0; kk < 2; ++kk)                        \
        bfr[ni][kk] = lds_frag(CURB, wn * 64 + ni * 16 + ln, kk * 64 + qd * 16); \
    _Pragma("unroll") for (int mi = 0; mi < 2; ++mi)                          \
      _Pragma("unroll") for (int kk = 0; kk < 2; ++kk)                        \
        af[mi][kk] = lds_frag(CURA, wm * 128 + mi * 16 + ln, kk * 64 + qd * 16); \
    if (p1_) stage_half(Ag, 0, K, (t_ + 1) << 6, OTHA, w, lane);              \
    asm volatile("s_waitcnt lgkmcnt(8)" ::: "memory");                        \
    __builtin_amdgcn_s_barrier();                                             \
    PH_MFMA(0)                                                                \
    _Pragma("unroll") for (int mi = 0; mi < 2; ++mi)                          \
      _Pragma("unroll") for (int kk = 0; kk < 2; ++kk)                        \
        af[mi][kk] = lds_frag(CURA, wm * 128 + (mi + 2) * 16 + ln, kk * 64 + qd * 16); \
    if (p1_) stage_half(Ag, 128, K, (t_ + 1) << 6, OTHA + 8192, w, lane);     \
    __builtin_amdgcn_s_barrier();                                             \
    PH_MFMA(2)                                                                \
    _Pragma("unroll") for (int mi = 0; mi < 2; ++mi)                          \
      _Pragma("unroll") for (int kk = 0; kk < 2; ++kk)                        \
        af[mi][kk] = lds_frag(CURA, wm * 128 + (mi + 4) * 16 + ln, kk * 64 + qd * 16); \
    if (p2_) stage_half(Bg, 0, K, (t_ + 2) << 6, CURB, w, lane);              \
    __builtin_amdgcn_s_barrier();                                             \
    PH_MFMA(4)                                                                \
    _Pragma("unroll") for (int mi = 0; mi < 2; ++mi)                          \
      _Pragma("unroll") for (int kk = 0; kk < 2; ++kk)                        \
        af[mi][kk] = lds_frag(CURA, wm * 128 + (mi + 6) * 16 + ln, kk * 64 + qd * 16); \
    if (p2_) {                                                                \
        stage_half(Bg, 128, K, (t_ + 2) << 6, CURB + 8192, w, lane);          \
        asm volatile("s_waitcnt vmcnt(4)" ::: "memory");                      \
    } else if (p1_) {                                                         \
        asm volatile("s_waitcnt vmcnt(0)" ::: "memory");                      \
    }                                                                         \
    __builtin_amdgcn_s_barrier();                                             \
    PH_MFMA(6)                                                                \
  }

template <int OUT_F32>
__global__ __launch_bounds__(512, 1) void gemm256(const u16* __restrict__ A,
                                                  const u16* __restrict__ Bt,
                                                  void* __restrict__ Cv,
                                                  int M, int N, int K) {
    __shared__ __align__(16) u16 As[2][16384];
    __shared__ __align__(16) u16 Bs[2][16384];

    int tid = threadIdx.x;
    int w = tid >> 6, lane = tid & 63;
    int ln = lane & 15, qd = lane >> 4;
    int wm = w >> 2, wn = w & 3;

    int nbx = N >> 8;
    int cpx = gridDim.x >> 3;
    int bid = blockIdx.x;
    int swz = (bid & 7) * cpx + (bid >> 3);
    int m0 = (swz / nbx) << 8;
    int n0 = (swz % nbx) << 8;

    const u16* Ag = A + (size_t)m0 * K;
    const u16* Bg = Bt + (size_t)n0 * K;
    int nt = K >> 6;

    f32x4 acc[8][4];
#pragma unroll
    for (int i = 0; i < 8; ++i)
#pragma unroll
        for (int j = 0; j < 4; ++j) acc[i][j] = f32x4{0.f, 0.f, 0.f, 0.f};

    u16* A0 = &As[0][0]; u16* A1v = &As[1][0];
    u16* B0 = &Bs[0][0]; u16* B1v = &Bs[1][0];

    stage_half(Ag, 0,   K, 0,  A0,         w, lane);
    stage_half(Ag, 128, K, 0,  A0 + 8192,  w, lane);
    stage_half(Bg, 0,   K, 0,  B0,         w, lane);
    stage_half(Bg, 128, K, 0,  B0 + 8192,  w, lane);
    stage_half(Bg, 0,   K, 64, B1v,        w, lane);
    stage_half(Bg, 128, K, 64, B1v + 8192, w, lane);
    asm volatile("s_waitcnt vmcnt(4)" ::: "memory");
    __builtin_amdgcn_s_barrier();

    for (int tt = 0; tt < nt; tt += 2) {
        TILE_BODY(tt,     A0,  B0,  A1v)
        TILE_BODY(tt + 1, A1v, B1v, A0)
    }

#pragma unroll
    for (int mi = 0; mi < 8; ++mi)
#pragma unroll
        for (int ni = 0; ni < 4; ++ni)
#pragma unroll
            for (int r = 0; r < 4; ++r) {
                int row = m0 + wm * 128 + mi * 16 + qd * 4 + r;
                int col = n0 + wn * 64 + ni * 16 + ln;
                if (OUT_F32)
                    ((float*)Cv)[(size_t)row * N + col] = acc[mi][ni][r];
                else
                    ((u16*)Cv)[(size_t)row * N + col] = f2bf(acc[mi][ni][r]);
            }
}

// ---------------- RoPE (merged Q+K, vectorized 8 u16/thread) ---------------
// Q is scaled by 1/sqrt(128)*log2(e): scores land in log2 domain for the
// attention kernel's exp2-based softmax (exact reparametrization).
__global__ __launch_bounds__(256) void rope_k(u16* __restrict__ Q,
                                              u16* __restrict__ Kb,
                                              float qscale) {
    const int ngq = B_ * S_ * NH_ * (HD_ / 8);   // groups of 4 pairs
    const int ngk = B_ * S_ * NKV_ * (HD_ / 8);
    int i = blockIdx.x * 256 + threadIdx.x;
    u16* buf; int nheads; float scale;
    if (i < ngq) { buf = Q; nheads = NH_; scale = qscale; }
    else {
        i -= ngq;
        if (i >= ngk) return;
        buf = Kb; nheads = NKV_; scale = 1.f;
    }
    int gp = i & 15;                 // group within head (pairs 4gp..4gp+3)
    int hh = (i >> 4) % nheads;
    int row = i / (16 * nheads);
    int s = row & (S_ - 1);
    size_t base = ((size_t)row * nheads + hh) * HD_ + gp * 8;
    uint4 v = *(const uint4*)&buf[base];
    unsigned ov[4];
    unsigned* vp = (unsigned*)&v;
#pragma unroll
    for (int j = 0; j < 4; ++j) {
        int p = gp * 4 + j;
        float freq = __expf(-(float)(2 * p) * (9.210340371976184f / 128.0f));
        float ang = (float)s * freq;
        float c, sn;
        sincosf(ang, &sn, &c);
        float x0 = bf2f((u16)vp[j]), x1 = bf2f((u16)(vp[j] >> 16));
        ov[j] = cvt_pk((x0 * c - x1 * sn) * scale, (x0 * sn + x1 * c) * scale);
    }
    *(uint4*)&buf[base] = *(uint4*)ov;
}

// ---------------- flash attention (transposed-S, log2-domain softmax) ------
// grid (S/256, NH, B), 512 threads (8 waves); block does qt=bx and qt=15-bx
// (constant 34 key-tiles -> perfect balance, 512 blocks = 2/CU).
// VALU diet: mask only on diagonal tiles (nfull split), exp2 softmax,
// defer-max (T13, THR=8 -> P<=256), HW cvt_pk packing, setprio on MFMA.
__global__ __launch_bounds__(512) void attn_k(const u16* __restrict__ Q,
                                              const u16* __restrict__ K,
                                              const u16* __restrict__ Vt,
                                              u16* __restrict__ AO) {
    __shared__ __align__(16) u16 Ks[2][64 * 136];    // [sk][d] pad->136
    __shared__ __align__(16) u16 Vts[2][128 * 72];   // [d][sk] pad->72

    int tid = threadIdx.x;
    int w = tid >> 6, lane = tid & 63;
    int ln = lane & 15, qd = lane >> 4;

    int h  = blockIdx.y;
    int b  = blockIdx.z;
    int g  = h >> 2;

    const u16* Kbase = K + (size_t)(b * S_) * (NKV_ * HD_) + g * HD_;
    const u16* Vtb   = Vt + ((size_t)(b * NKV_ + g)) * HD_ * S_;

    int kr0 = tid >> 4, kb0 = (tid & 15) * 8;
    int kr1 = (tid + 512) >> 4, kb1 = kb0;
    int vr0 = tid >> 3, vb0 = (tid & 7) * 8;
    int vr1 = (tid + 512) >> 3, vb1 = vb0;

    for (int pass = 0; pass < 2; ++pass) {
        int qt = pass ? (S_ / 128 - 1 - (int)blockIdx.x) : (int)blockIdx.x;
        int q0 = qt * 128;
        int qb = q0 + w * 16;            // wave q base
        int qg = qb + ln;                // lane's q row
        int ntw   = ((qb + 15) >> 6) + 1;  // active tiles for this wave
        int nfull = (qb + 1) >> 6;         // fully-unmasked tiles

        const u16* qptr = Q + ((size_t)(b * S_ + qg)) * (NH_ * HD_) + h * HD_;
        short8 bq[4];
#pragma unroll
        for (int kq = 0; kq < 4; ++kq)
            bq[kq] = *(const short8*)(qptr + kq * 32 + qd * 8);

        f32x4 ot[8];
#pragma unroll
        for (int db = 0; db < 8; ++db) ot[db] = f32x4{0.f, 0.f, 0.f, 0.f};
        float m_s = -1e30f, l_s = 0.f;

        int nk = 2 * qt + 2;

        {
            int4 a0 = *(const int4*)(Kbase + (size_t)kr0 * (NKV_ * HD_) + kb0);
            int4 a1 = *(const int4*)(Kbase + (size_t)kr1 * (NKV_ * HD_) + kb1);
            int4 v0 = *(const int4*)(Vtb + (size_t)vr0 * S_ + vb0);
            int4 v1 = *(const int4*)(Vtb + (size_t)vr1 * S_ + vb1);
            *(int4*)&Ks[0][kr0 * 136 + kb0] = a0;
            *(int4*)&Ks[0][kr1 * 136 + kb1] = a1;
            *(int4*)&Vts[0][vr0 * 72 + vb0] = v0;
            *(int4*)&Vts[0][vr1 * 72 + vb1] = v1;
        }
        __syncthreads();

        for (int kt = 0; kt < nk; ++kt) {
            int bb = kt & 1;
            int k0 = kt * 64;
            bool pf = (kt + 1 < nk);
            int4 pa0, pa1, pv0, pv1;
            if (pf) {
                int k0n = k0 + 64;
                pa0 = *(const int4*)(Kbase + (size_t)(k0n + kr0) * (NKV_ * HD_) + kb0);
                pa1 = *(const int4*)(Kbase + (size_t)(k0n + kr1) * (NKV_ * HD_) + kb1);
                pv0 = *(const int4*)(Vtb + (size_t)vr0 * S_ + k0n + vb0);
                pv1 = *(const int4*)(Vtb + (size_t)vr1 * S_ + k0n + vb1);
            }

            if (kt < ntw) {
                // S^T = K Q^T
                f32x4 st[4];
#pragma unroll
                for (int kb = 0; kb < 4; ++kb) st[kb] = f32x4{0.f, 0.f, 0.f, 0.f};
                __builtin_amdgcn_s_setprio(1);
#pragma unroll
                for (int kb = 0; kb < 4; ++kb)
#pragma unroll
                    for (int kq = 0; kq < 4; ++kq) {
                        short8 ak = *(const short8*)&Ks[bb][(kb * 16 + ln) * 136 + kq * 32 + qd * 8];
                        st[kb] = __builtin_amdgcn_mfma_f32_16x16x32_bf16(ak, bq[kq], st[kb], 0, 0, 0);
                    }
                __builtin_amdgcn_s_setprio(0);

                float mx;
                if (kt >= nfull) {          // diagonal tile: mask + max
                    int lim = qg - k0 - qd * 4;   // masked iff 16*kb + r > lim
                    mx = -1e30f;
#pragma unroll
                    for (int kb = 0; kb < 4; ++kb)
#pragma unroll
                        for (int r = 0; r < 4; ++r) {
                            if (16 * kb + r > lim) st[kb][r] = -1e30f;
                            mx = fmaxf(mx, st[kb][r]);
                        }
                } else {                    // full tile: max only
                    mx = st[0][0];
#pragma unroll
                    for (int kb = 0; kb < 4; ++kb)
#pragma unroll
                        for (int r = 0; r < 4; ++r)
                            if (kb + r) mx = fmaxf(mx, st[kb][r]);
                }
                mx = fmaxf(mx, __shfl_xor(mx, 16, 64));
                mx = fmaxf(mx, __shfl_xor(mx, 32, 64));

                // T13 defer-max: only rescale when the max grew by > 8 (log2)
                if (__any(mx > m_s + 8.f)) {
                    float mn = fmaxf(m_s, mx);
                    float alpha = exp2_fast(m_s - mn);
                    m_s = mn;
                    l_s *= alpha;
#pragma unroll
                    for (int db = 0; db < 8; ++db)
#pragma unroll
                        for (int r = 0; r < 4; ++r) ot[db][r] *= alpha;
                }
                float rs = 0.f;
#pragma unroll
                for (int kb = 0; kb < 4; ++kb)
#pragma unroll
                    for (int r = 0; r < 4; ++r) {
                        float pv = exp2_fast(st[kb][r] - m_s);
                        st[kb][r] = pv;
                        rs += pv;
                    }
                rs += __shfl_xor(rs, 16, 64);
                rs += __shfl_xor(rs, 32, 64);
                l_s += rs;

                unsigned pk[4][2];
#pragma unroll
                for (int kb = 0; kb < 4; ++kb) {
                    pk[kb][0] = cvt_pk(st[kb][0], st[kb][1]);
                    pk[kb][1] = cvt_pk(st[kb][2], st[kb][3]);
                }
                int sA = ((qd & 1) << 5) + ln;
                int sB = sA + 16;
                bool hi = (qd & 2) != 0;
#pragma unroll
                for (int ks = 0; ks < 2; ++ks) {
                    unsigned t0a = (unsigned)__shfl((int)pk[2 * ks][0], sA, 64);
                    unsigned t0b = (unsigned)__shfl((int)pk[2 * ks][1], sA, 64);
                    unsigned t1a = (unsigned)__shfl((int)pk[2 * ks + 1][0], sA, 64);
                    unsigned t1b = (unsigned)__shfl((int)pk[2 * ks + 1][1], sA, 64);
                    unsigned t2a = (unsigned)__shfl((int)pk[2 * ks][0], sB, 64);
                    unsigned t2b = (unsigned)__shfl((int)pk[2 * ks][1], sB, 64);
                    unsigned t3a = (unsigned)__shfl((int)pk[2 * ks + 1][0], sB, 64);
                    unsigned t3b = (unsigned)__shfl((int)pk[2 * ks + 1][1], sB, 64);
                    union { unsigned u[4]; short8 s8; } bp;
                    bp.u[0] = hi ? t1a : t0a;
                    bp.u[1] = hi ? t1b : t0b;
                    bp.u[2] = hi ? t3a : t2a;
                    bp.u[3] = hi ? t3b : t2b;
                    __builtin_amdgcn_s_setprio(1);
#pragma unroll
                    for (int db = 0; db < 8; ++db) {
                        short8 av = *(const short8*)&Vts[bb][(db * 16 + ln) * 72 + ks * 32 + qd * 8];
                        ot[db] = __builtin_amdgcn_mfma_f32_16x16x32_bf16(av, bp.s8, ot[db], 0, 0, 0);
                    }
                    __builtin_amdgcn_s_setprio(0);
                }
            }

            if (pf) {
                int nb2 = bb ^ 1;
                *(int4*)&Ks[nb2][kr0 * 136 + kb0] = pa0;
                *(int4*)&Ks[nb2][kr1 * 136 + kb1] = pa1;
                *(int4*)&Vts[nb2][vr0 * 72 + vb0] = pv0;
                *(int4*)&Vts[nb2][vr1 * 72 + vb1] = pv1;
            }
            __syncthreads();
        }

        float invl = 1.0f / l_s;
        size_t orow = (size_t)(b * S_ + qg) * (NH_ * HD_) + h * HD_;
#pragma unroll
        for (int db = 0; db < 8; ++db) {
            uint2 t2;
            t2.x = cvt_pk(ot[db][0] * invl, ot[db][1] * invl);
            t2.y = cvt_pk(ot[db][2] * invl, ot[db][3] * invl);
            *(uint2*)&AO[orow + db * 16 + qd * 4] = t2;
        }
    }
}

extern "C" void kernel_launch(void* const* d_in, const int* in_sizes, int n_in,
                              void* d_out, int out_size, void* d_ws, size_t ws_size,
                              hipStream_t stream) {
    const float* x  = (const float*)d_in[0];
    const float* wq = (const float*)d_in[1];
    const float* wk = (const float*)d_in[2];
    const float* wv = (const float*)d_in[3];
    const float* wo = (const float*)d_in[4];
    float* out = (float*)d_out;

    char* p = (char*)d_ws;
    auto alloc = [&](size_t nelem) { u16* r = (u16*)p; p += nelem * 2; return r; };
    u16* xb  = alloc(4096ull * 4096);   // aliased by woT after projections
    u16* wqT = alloc(4096ull * 4096);   // aliased by Vt after projections
    u16* wkT = alloc(1024ull * 4096);   // contiguous with wvT (gemm_kv relies on it)
    u16* wvT = alloc(1024ull * 4096);
    u16* Q   = alloc(4096ull * 4096);
    u16* Kb  = alloc(4096ull * 1024);
    u16* Vb  = alloc(4096ull * 1024);
    u16* AO  = alloc(4096ull * 4096);

    dim3 tblk(64, 4);
    conv_k<<<16384, 256, 0, stream>>>(x, xb);
    tconv_k<<<dim3(64, 64), tblk, 0, stream>>>(wq, wqT, 4096, 4096);
    tconv2_k<<<dim3(16, 64, 2), tblk, 0, stream>>>(wk, wv, wkT, wvT, 4096, 1024);

    gemm256<0><<<256, 512, 0, stream>>>(xb, wqT, Q, 4096, 4096, 4096);
    gemm_kv<<<dim3(16, 32), 256, 0, stream>>>(xb, wkT, Kb, Vb, 4096, 4096);

    u16* woT = xb;
    u16* Vt  = wqT;
    tconv_k<<<dim3(64, 64), tblk, 0, stream>>>(wo, woT, 4096, 4096);

    // Q scale = 1/sqrt(128) * log2(e)  (log2-domain softmax in attn_k)
    int ng = B_ * S_ * NH_ * (HD_ / 8) + B_ * S_ * NKV_ * (HD_ / 8);
    rope_k<<<(ng + 255) / 256, 256, 0, stream>>>(Q, Kb, 0.12751743f);

    transpose_k<<<dim3(16, 32, 2), tblk, 0, stream>>>(Vb, Vt, S_, NKV_ * HD_);

    attn_k<<<dim3(S_ / 256, NH_, B_), 512, 0, stream>>>(Q, Kb, Vt, AO);

    gemm256<1><<<256, 512, 0, stream>>>(AO, woT, out, 4096, 4096, 4096);
}

// Round 4
// 727.932 us; speedup vs baseline: 1.4926x; 1.0389x over previous
//
#include <hip/hip_runtime.h>
#include <hip/hip_bf16.h>

#define B_ 2
#define S_ 2048
#define D_ 4096
#define NH_ 32
#define NKV_ 8
#define HD_ 128
#define NREP_ 4

typedef unsigned short u16;
typedef __attribute__((ext_vector_type(8))) short short8;
typedef __attribute__((ext_vector_type(4))) float f32x4;

__device__ inline float bf2f(u16 u) {
    union { unsigned u; float f; } v; v.u = ((unsigned)u) << 16; return v.f;
}
__device__ inline u16 f2bf(float f) {
    union { float f; unsigned u; } v; v.f = f;
    unsigned r = v.u + 0x7fffu + ((v.u >> 16) & 1u);
    return (u16)(r >> 16);
}
// HW packed f32x2 -> bf16x2 (RNE), one instr (T12 primitive)
__device__ inline unsigned cvt_pk(float lo, float hi) {
    unsigned r;
    asm("v_cvt_pk_bf16_f32 %0, %1, %2" : "=v"(r) : "v"(lo), "v"(hi));
    return r;
}
// v_exp_f32 = 2^x
__device__ inline float exp2_fast(float x) {
    float r;
    asm("v_exp_f32 %0, %1" : "=v"(r) : "v"(x));
    return r;
}

// async global->LDS, 16 bytes/lane (m97-verified). LDS base wave-uniform.
__device__ inline void gl_lds16(const u16* g, u16* l) {
    __builtin_amdgcn_global_load_lds(
        (const __attribute__((address_space(1))) unsigned int*)g,
        (__attribute__((address_space(3))) unsigned int*)l, 16, 0, 0);
}

// ---------------- elementwise f32 -> bf16 ----------------------------------
__global__ __launch_bounds__(256) void conv_k(const float* __restrict__ in,
                                              u16* __restrict__ out) {
    size_t i = ((size_t)blockIdx.x * 256 + threadIdx.x) * 4;
    float4 v = *(const float4*)&in[i];
    uint2 t;
    t.x = cvt_pk(v.x, v.y);
    t.y = cvt_pk(v.z, v.w);
    *(uint2*)&out[i] = t;
}

// ---------------- transpose+convert: f32 in [R][C] -> bf16 out [C][R] ------
__global__ __launch_bounds__(256) void tconv_k(const float* __restrict__ in,
                                               u16* __restrict__ out,
                                               int R, int C) {
    __shared__ u16 tile[64][65];
    int bx = blockIdx.x * 64, by = blockIdx.y * 64;
    int tx = threadIdx.x, ty = threadIdx.y;
    for (int i = ty; i < 64; i += 4)
        tile[i][tx] = f2bf(in[(size_t)(by + i) * C + bx + tx]);
    __syncthreads();
    for (int i = ty; i < 64; i += 4)
        out[(size_t)(bx + i) * R + by + tx] = tile[tx][i];
}

// z-batched variant: z=0 -> in0/out0, z=1 -> in1/out1
__global__ __launch_bounds__(256) void tconv2_k(const float* __restrict__ in0,
                                                const float* __restrict__ in1,
                                                u16* __restrict__ out0,
                                                u16* __restrict__ out1,
                                                int R, int C) {
    __shared__ u16 tile[64][65];
    const float* in = blockIdx.z ? in1 : in0;
    u16* out = blockIdx.z ? out1 : out0;
    int bx = blockIdx.x * 64, by = blockIdx.y * 64;
    int tx = threadIdx.x, ty = threadIdx.y;
    for (int i = ty; i < 64; i += 4)
        tile[i][tx] = f2bf(in[(size_t)(by + i) * C + bx + tx]);
    __syncthreads();
    for (int i = ty; i < 64; i += 4)
        out[(size_t)(bx + i) * R + by + tx] = tile[tx][i];
}

// ---------------- transpose bf16 (z-batched): in [R][C] -> out [C][R] ------
__global__ __launch_bounds__(256) void transpose_k(const u16* __restrict__ in,
                                                   u16* __restrict__ out,
                                                   int R, int C) {
    __shared__ u16 tile[64][65];
    const u16* ib = in + (size_t)blockIdx.z * R * C;
    u16* ob = out + (size_t)blockIdx.z * R * C;
    int bx = blockIdx.x * 64, by = blockIdx.y * 64;
    int tx = threadIdx.x, ty = threadIdx.y;
    for (int i = ty; i < 64; i += 4)
        tile[i][tx] = ib[(size_t)(by + i) * C + bx + tx];
    __syncthreads();
    for (int i = ty; i < 64; i += 4)
        ob[(size_t)(bx + i) * R + by + tx] = tile[tx][i];
}

// ---------------- merged K+V projection GEMM (m97 structure) ---------------
// Bt = wkT(1024 rows) || wvT(1024 rows), contiguous. N=2048.
// Output: cols 0-1023 -> Kout, 1024-2047 -> Vout (both row stride 1024).
__global__ __launch_bounds__(256) void gemm_kv(const u16* __restrict__ A,
                                               const u16* __restrict__ Bt,
                                               u16* __restrict__ Kout,
                                               u16* __restrict__ Vout,
                                               int M, int K) {
    __shared__ __align__(16) u16 As[128 * 32];
    __shared__ __align__(16) u16 Bs[128 * 32];
    int tid = threadIdx.x;
    int w = tid >> 6, lane = tid & 63;
    int ln = lane & 15, qd = lane >> 4;
    int wr = w >> 1, wc = w & 1;
    int m0 = blockIdx.y * 128, n0 = blockIdx.x * 128;

    int srow = lane >> 2;
    int skk  = (lane & 3) * 8;
    const u16* Ag = A  + (size_t)(m0 + w * 32 + srow) * K + skk;
    const u16* Bg = Bt + (size_t)(n0 + w * 32 + srow) * K + skk;

    f32x4 acc[4][4];
#pragma unroll
    for (int i = 0; i < 4; ++i)
#pragma unroll
        for (int j = 0; j < 4; ++j)
            acc[i][j] = f32x4{0.f, 0.f, 0.f, 0.f};

    for (int k0 = 0; k0 < K; k0 += 32) {
#pragma unroll
        for (int t = 0; t < 2; ++t) {
            gl_lds16(Ag + (size_t)(t * 16) * K + k0, &As[(w * 32 + t * 16) * 32]);
            gl_lds16(Bg + (size_t)(t * 16) * K + k0, &Bs[(w * 32 + t * 16) * 32]);
        }
        __syncthreads();
        short8 af[4], bfr[4];
#pragma unroll
        for (int i = 0; i < 4; ++i)
            af[i] = *(const short8*)&As[(wr * 64 + i * 16 + ln) * 32 + qd * 8];
#pragma unroll
        for (int j = 0; j < 4; ++j)
            bfr[j] = *(const short8*)&Bs[(wc * 64 + j * 16 + ln) * 32 + qd * 8];
#pragma unroll
        for (int i = 0; i < 4; ++i)
#pragma unroll
            for (int j = 0; j < 4; ++j)
                acc[i][j] = __builtin_amdgcn_mfma_f32_16x16x32_bf16(af[i], bfr[j], acc[i][j], 0, 0, 0);
        __syncthreads();
    }
    u16* dst = (n0 < 1024) ? Kout : Vout;
    int nb = (n0 < 1024) ? n0 : (n0 - 1024);
#pragma unroll
    for (int i = 0; i < 4; ++i)
#pragma unroll
        for (int j = 0; j < 4; ++j)
#pragma unroll
            for (int r = 0; r < 4; ++r) {
                int row = m0 + wr * 64 + i * 16 + qd * 4 + r;
                int col = nb + wc * 64 + j * 16 + ln;
                dst[(size_t)row * 1024 + col] = f2bf(acc[i][j][r]);
            }
}

// ---------------- GEMM 256^2 8-phase (m201 template, T2+T3+T4+T5) ----------
// (unchanged — verified)
__device__ inline short8 lds_frag(const u16* base, int row, int colb) {
    int lin = ((row & 127) << 7) + colb;
    int off = ((row >> 7) << 14) + (lin ^ (((lin >> 9) & 1) << 5));
    return *(const short8*)((const char*)base + off);
}

__device__ inline void stage_half(const u16* g, int row0, int ldK, int k0,
                                  u16* ldsHalf, int w, int lane) {
#pragma unroll
    for (int j = 0; j < 2; ++j) {
        int Lb = (w << 11) + (j << 10) + (lane << 4);    // linear dest byte
        int src = Lb ^ (((Lb >> 9) & 1) << 5);           // inverse-swizzled src
        const u16* gp = g + (size_t)(row0 + (src >> 7)) * ldK + k0 + ((src & 127) >> 1);
        gl_lds16(gp, ldsHalf + (((w << 11) + (j << 10)) >> 1));
    }
}

#define PH_MFMA(MB)                                                           \
    asm volatile("s_waitcnt lgkmcnt(0)" ::: "memory");                        \
    __builtin_amdgcn_sched_barrier(0);                                        \
    __builtin_amdgcn_s_setprio(1);                                            \
    _Pragma("unroll") for (int mi = 0; mi < 2; ++mi)                          \
      _Pragma("unroll") for (int ni = 0; ni < 4; ++ni)                        \
        _Pragma("unroll") for (int kk = 0; kk < 2; ++kk)                      \
          acc[(MB) + mi][ni] = __builtin_amdgcn_mfma_f32_16x16x32_bf16(       \
              af[mi][kk], bfr[ni][kk], acc[(MB) + mi][ni], 0, 0, 0);          \
    __builtin_amdgcn_s_setprio(0);                                            \
    __builtin_amdgcn_s_barrier();

#define TILE_BODY(T, CURA, CURB, OTHA)                                        \
  {                                                                           \
    const int t_ = (T);                                                       \
    const bool p1_ = (t_ + 1 < nt), p2_ = (t_ + 2 < nt);                      \
    short8 bfr[4][2], af[2][2];                                               \
    _Pragma("unroll") for (int ni = 0; ni < 4; ++ni)                          \
      _Pragma("unroll") for (int kk = 0; kk < 2; ++kk)                        \
        bfr[ni][kk] = lds_frag(CURB, wn * 64 + ni * 16 + ln, kk * 64 + qd * 16); \
    _Pragma("unroll") for (int mi = 0; mi < 2; ++mi)                          \
      _Pragma("unroll") for (int kk = 0; kk < 2; ++kk)                        \
        af[mi][kk] = lds_frag(CURA, wm * 128 + mi * 16 + ln, kk * 64 + qd * 16); \
    if (p1_) stage_half(Ag, 0, K, (t_ + 1) << 6, OTHA, w, lane);              \
    asm volatile("s_waitcnt lgkmcnt(8)" ::: "memory");                        \
    __builtin_amdgcn_s_barrier();                                             \
    PH_MFMA(0)                                                                \
    _Pragma("unroll") for (int mi = 0; mi < 2; ++mi)                          \
      _Pragma("unroll") for (int kk = 0; kk < 2; ++kk)                        \
        af[mi][kk] = lds_frag(CURA, wm * 128 + (mi + 2) * 16 + ln, kk * 64 + qd * 16); \
    if (p1_) stage_half(Ag, 128, K, (t_ + 1) << 6, OTHA + 8192, w, lane);     \
    __builtin_amdgcn_s_barrier();                                             \
    PH_MFMA(2)                                                                \
    _Pragma("unroll") for (int mi = 0; mi < 2; ++mi)                          \
      _Pragma("unroll") for (int kk = 0; kk < 2; ++kk)                        \
        af[mi][kk] = lds_frag(CURA, wm * 128 + (mi + 4) * 16 + ln, kk * 64 + qd * 16); \
    if (p2_) stage_half(Bg, 0, K, (t_ + 2) << 6, CURB, w, lane);              \
    __builtin_amdgcn_s_barrier();                                             \
    PH_MFMA(4)                                                                \
    _Pragma("unroll") for (int mi = 0; mi < 2; ++mi)                          \
      _Pragma("unroll") for (int kk = 0; kk < 2; ++kk)                        \
        af[mi][kk] = lds_frag(CURA, wm * 128 + (mi + 6) * 16 + ln, kk * 64 + qd * 16); \
    if (p2_) {                                                                \
        stage_half(Bg, 128, K, (t_ + 2) << 6, CURB + 8192, w, lane);          \
        asm volatile("s_waitcnt vmcnt(4)" ::: "memory");                      \
    } else if (p1_) {                                                         \
        asm volatile("s_waitcnt vmcnt(0)" ::: "memory");                      \
    }                                                                         \
    __builtin_amdgcn_s_barrier();                                             \
    PH_MFMA(6)                                                                \
  }

template <int OUT_F32>
__global__ __launch_bounds__(512, 1) void gemm256(const u16* __restrict__ A,
                                                  const u16* __restrict__ Bt,
                                                  void* __restrict__ Cv,
                                                  int M, int N, int K) {
    __shared__ __align__(16) u16 As[2][16384];
    __shared__ __align__(16) u16 Bs[2][16384];

    int tid = threadIdx.x;
    int w = tid >> 6, lane = tid & 63;
    int ln = lane & 15, qd = lane >> 4;
    int wm = w >> 2, wn = w & 3;

    int nbx = N >> 8;
    int cpx = gridDim.x >> 3;
    int bid = blockIdx.x;
    int swz = (bid & 7) * cpx + (bid >> 3);
    int m0 = (swz / nbx) << 8;
    int n0 = (swz % nbx) << 8;

    const u16* Ag = A + (size_t)m0 * K;
    const u16* Bg = Bt + (size_t)n0 * K;
    int nt = K >> 6;

    f32x4 acc[8][4];
#pragma unroll
    for (int i = 0; i < 8; ++i)
#pragma unroll
        for (int j = 0; j < 4; ++j) acc[i][j] = f32x4{0.f, 0.f, 0.f, 0.f};

    u16* A0 = &As[0][0]; u16* A1v = &As[1][0];
    u16* B0 = &Bs[0][0]; u16* B1v = &Bs[1][0];

    stage_half(Ag, 0,   K, 0,  A0,         w, lane);
    stage_half(Ag, 128, K, 0,  A0 + 8192,  w, lane);
    stage_half(Bg, 0,   K, 0,  B0,         w, lane);
    stage_half(Bg, 128, K, 0,  B0 + 8192,  w, lane);
    stage_half(Bg, 0,   K, 64, B1v,        w, lane);
    stage_half(Bg, 128, K, 64, B1v + 8192, w, lane);
    asm volatile("s_waitcnt vmcnt(4)" ::: "memory");
    __builtin_amdgcn_s_barrier();

    for (int tt = 0; tt < nt; tt += 2) {
        TILE_BODY(tt,     A0,  B0,  A1v)
        TILE_BODY(tt + 1, A1v, B1v, A0)
    }

#pragma unroll
    for (int mi = 0; mi < 8; ++mi)
#pragma unroll
        for (int ni = 0; ni < 4; ++ni)
#pragma unroll
            for (int r = 0; r < 4; ++r) {
                int row = m0 + wm * 128 + mi * 16 + qd * 4 + r;
                int col = n0 + wn * 64 + ni * 16 + ln;
                if (OUT_F32)
                    ((float*)Cv)[(size_t)row * N + col] = acc[mi][ni][r];
                else
                    ((u16*)Cv)[(size_t)row * N + col] = f2bf(acc[mi][ni][r]);
            }
}

// ---------------- RoPE (merged Q+K, vectorized 8 u16/thread) ---------------
// Q is scaled by 1/sqrt(128)*log2(e): scores land in log2 domain for the
// attention kernel's exp2-based softmax (exact reparametrization).
__global__ __launch_bounds__(256) void rope_k(u16* __restrict__ Q,
                                              u16* __restrict__ Kb,
                                              float qscale) {
    const int ngq = B_ * S_ * NH_ * (HD_ / 8);   // groups of 4 pairs
    const int ngk = B_ * S_ * NKV_ * (HD_ / 8);
    int i = blockIdx.x * 256 + threadIdx.x;
    u16* buf; int nheads; float scale;
    if (i < ngq) { buf = Q; nheads = NH_; scale = qscale; }
    else {
        i -= ngq;
        if (i >= ngk) return;
        buf = Kb; nheads = NKV_; scale = 1.f;
    }
    int gp = i & 15;                 // group within head (pairs 4gp..4gp+3)
    int hh = (i >> 4) % nheads;
    int row = i / (16 * nheads);
    int s = row & (S_ - 1);
    size_t base = ((size_t)row * nheads + hh) * HD_ + gp * 8;
    uint4 v = *(const uint4*)&buf[base];
    unsigned ov[4];
    unsigned* vp = (unsigned*)&v;
#pragma unroll
    for (int j = 0; j < 4; ++j) {
        int p = gp * 4 + j;
        float freq = __expf(-(float)(2 * p) * (9.210340371976184f / 128.0f));
        float ang = (float)s * freq;
        float c, sn;
        sincosf(ang, &sn, &c);
        float x0 = bf2f((u16)vp[j]), x1 = bf2f((u16)(vp[j] >> 16));
        ov[j] = cvt_pk((x0 * c - x1 * sn) * scale, (x0 * sn + x1 * c) * scale);
    }
    *(uint4*)&buf[base] = *(uint4*)ov;
}

// ---------------- flash attention (transposed-S, log2-domain softmax) ------
// grid (S/256, NH, B), 512 threads (8 waves); block does qt=bx and qt=15-bx
// (constant 34 key-tiles). LDS cut to 64KB exactly (unpadded tiles + XOR
// swizzle byte^=((row&7)<<4)) so TWO blocks co-reside per CU (the 70KB
// version was 1 block/CU -> latency-bound at 2 waves/SIMD).
// Bank check (all four patterns): 8 lanes x 16B per 4-bank group = 8 cyc/wave
// = optimal, same as the old padded layout.
__global__ __launch_bounds__(512, 4) void attn_k(const u16* __restrict__ Q,
                                                 const u16* __restrict__ K,
                                                 const u16* __restrict__ Vt,
                                                 u16* __restrict__ AO) {
    __shared__ __align__(16) u16 Ks[2][64 * 128];    // [sk][d] swizzled, 16KB/buf
    __shared__ __align__(16) u16 Vts[2][128 * 64];   // [d][sk] swizzled, 16KB/buf

    int tid = threadIdx.x;
    int w = tid >> 6, lane = tid & 63;
    int ln = lane & 15, qd = lane >> 4;
    int sw = (ln & 7) << 4;          // read-side XOR (row&7 == ln&7)

    int h  = blockIdx.y;
    int b  = blockIdx.z;
    int g  = h >> 2;

    const u16* Kbase = K + (size_t)(b * S_) * (NKV_ * HD_) + g * HD_;
    const u16* Vtb   = Vt + ((size_t)(b * NKV_ + g)) * HD_ * S_;

    // staging map: K rows kr0,kr0+32 (col 16B x (tid&15)); V rows vr0,vr0+64
    int kr0 = tid >> 4;
    int kg0 = (tid & 15) * 8;                       // u16 col (global)
    int kcs = (kg0 * 2) ^ ((kr0 & 7) << 4);         // swizzled LDS byte col
    int vr0 = tid >> 3;
    int vg0 = (tid & 7) * 8;
    int vcs = (vg0 * 2) ^ ((vr0 & 7) << 4);

    for (int pass = 0; pass < 2; ++pass) {
        int qt = pass ? (S_ / 128 - 1 - (int)blockIdx.x) : (int)blockIdx.x;
        int q0 = qt * 128;
        int qb = q0 + w * 16;            // wave q base
        int qg = qb + ln;                // lane's q row
        int ntw   = ((qb + 15) >> 6) + 1;  // active tiles for this wave
        int nfull = (qb + 1) >> 6;         // fully-unmasked tiles

        const u16* qptr = Q + ((size_t)(b * S_ + qg)) * (NH_ * HD_) + h * HD_;
        short8 bq[4];
#pragma unroll
        for (int kq = 0; kq < 4; ++kq)
            bq[kq] = *(const short8*)(qptr + kq * 32 + qd * 8);

        f32x4 ot[8];
#pragma unroll
        for (int db = 0; db < 8; ++db) ot[db] = f32x4{0.f, 0.f, 0.f, 0.f};
        float m_s = -1e30f, l_s = 0.f;

        int nk = 2 * qt + 2;

        {
            int4 a0 = *(const int4*)(Kbase + (size_t)kr0 * (NKV_ * HD_) + kg0);
            int4 a1 = *(const int4*)(Kbase + (size_t)(kr0 + 32) * (NKV_ * HD_) + kg0);
            int4 v0 = *(const int4*)(Vtb + (size_t)vr0 * S_ + vg0);
            int4 v1 = *(const int4*)(Vtb + (size_t)(vr0 + 64) * S_ + vg0);
            *(int4*)((char*)&Ks[0][0] + kr0 * 256 + kcs) = a0;
            *(int4*)((char*)&Ks[0][0] + (kr0 + 32) * 256 + kcs) = a1;
            *(int4*)((char*)&Vts[0][0] + vr0 * 128 + vcs) = v0;
            *(int4*)((char*)&Vts[0][0] + (vr0 + 64) * 128 + vcs) = v1;
        }
        __syncthreads();

        for (int kt = 0; kt < nk; ++kt) {
            int bb = kt & 1;
            int k0 = kt * 64;
            bool pf = (kt + 1 < nk);
            int4 pa0, pa1, pv0, pv1;
            if (pf) {
                int k0n = k0 + 64;
                pa0 = *(const int4*)(Kbase + (size_t)(k0n + kr0) * (NKV_ * HD_) + kg0);
                pa1 = *(const int4*)(Kbase + (size_t)(k0n + kr0 + 32) * (NKV_ * HD_) + kg0);
                pv0 = *(const int4*)(Vtb + (size_t)vr0 * S_ + k0n + vg0);
                pv1 = *(const int4*)(Vtb + (size_t)(vr0 + 64) * S_ + k0n + vg0);
            }

            if (kt < ntw) {
                // S^T = K Q^T
                f32x4 st[4];
#pragma unroll
                for (int kb = 0; kb < 4; ++kb) st[kb] = f32x4{0.f, 0.f, 0.f, 0.f};
                __builtin_amdgcn_s_setprio(1);
#pragma unroll
                for (int kb = 0; kb < 4; ++kb)
#pragma unroll
                    for (int kq = 0; kq < 4; ++kq) {
                        short8 ak = *(const short8*)((const char*)&Ks[bb][0] +
                                    (kb * 16 + ln) * 256 + ((kq * 64 + qd * 16) ^ sw));
                        st[kb] = __builtin_amdgcn_mfma_f32_16x16x32_bf16(ak, bq[kq], st[kb], 0, 0, 0);
                    }
                __builtin_amdgcn_s_setprio(0);

                float mx;
                if (kt >= nfull) {          // diagonal tile: mask + max
                    int lim = qg - k0 - qd * 4;   // masked iff 16*kb + r > lim
                    mx = -1e30f;
#pragma unroll
                    for (int kb = 0; kb < 4; ++kb)
#pragma unroll
                        for (int r = 0; r < 4; ++r) {
                            if (16 * kb + r > lim) st[kb][r] = -1e30f;
                            mx = fmaxf(mx, st[kb][r]);
                        }
                } else {                    // full tile: max only
                    mx = st[0][0];
#pragma unroll
                    for (int kb = 0; kb < 4; ++kb)
#pragma unroll
                        for (int r = 0; r < 4; ++r)
                            if (kb + r) mx = fmaxf(mx, st[kb][r]);
                }
                mx = fmaxf(mx, __shfl_xor(mx, 16, 64));
                mx = fmaxf(mx, __shfl_xor(mx, 32, 64));

                // T13 defer-max: only rescale when the max grew by > 8 (log2)
                if (__any(mx > m_s + 8.f)) {
                    float mn = fmaxf(m_s, mx);
                    float alpha = exp2_fast(m_s - mn);
                    m_s = mn;
                    l_s *= alpha;
#pragma unroll
                    for (int db = 0; db < 8; ++db)
#pragma unroll
                        for (int r = 0; r < 4; ++r) ot[db][r] *= alpha;
                }
                float rs = 0.f;
#pragma unroll
                for (int kb = 0; kb < 4; ++kb)
#pragma unroll
                    for (int r = 0; r < 4; ++r) {
                        float pv = exp2_fast(st[kb][r] - m_s);
                        st[kb][r] = pv;
                        rs += pv;
                    }
                rs += __shfl_xor(rs, 16, 64);
                rs += __shfl_xor(rs, 32, 64);
                l_s += rs;

                unsigned pk[4][2];
#pragma unroll
                for (int kb = 0; kb < 4; ++kb) {
                    pk[kb][0] = cvt_pk(st[kb][0], st[kb][1]);
                    pk[kb][1] = cvt_pk(st[kb][2], st[kb][3]);
                }
                int sA = ((qd & 1) << 5) + ln;
                int sB = sA + 16;
                bool hi = (qd & 2) != 0;
#pragma unroll
                for (int ks = 0; ks < 2; ++ks) {
                    unsigned t0a = (unsigned)__shfl((int)pk[2 * ks][0], sA, 64);
                    unsigned t0b = (unsigned)__shfl((int)pk[2 * ks][1], sA, 64);
                    unsigned t1a = (unsigned)__shfl((int)pk[2 * ks + 1][0], sA, 64);
                    unsigned t1b = (unsigned)__shfl((int)pk[2 * ks + 1][1], sA, 64);
                    unsigned t2a = (unsigned)__shfl((int)pk[2 * ks][0], sB, 64);
                    unsigned t2b = (unsigned)__shfl((int)pk[2 * ks][1], sB, 64);
                    unsigned t3a = (unsigned)__shfl((int)pk[2 * ks + 1][0], sB, 64);
                    unsigned t3b = (unsigned)__shfl((int)pk[2 * ks + 1][1], sB, 64);
                    union { unsigned u[4]; short8 s8; } bp;
                    bp.u[0] = hi ? t1a : t0a;
                    bp.u[1] = hi ? t1b : t0b;
                    bp.u[2] = hi ? t3a : t2a;
                    bp.u[3] = hi ? t3b : t2b;
                    __builtin_amdgcn_s_setprio(1);
#pragma unroll
                    for (int db = 0; db < 8; ++db) {
                        short8 av = *(const short8*)((const char*)&Vts[bb][0] +
                                    (db * 16 + ln) * 128 + ((ks * 64 + qd * 16) ^ sw));
                        ot[db] = __builtin_amdgcn_mfma_f32_16x16x32_bf16(av, bp.s8, ot[db], 0, 0, 0);
                    }
                    __builtin_amdgcn_s_setprio(0);
                }
            }

            if (pf) {
                int nb2 = bb ^ 1;
                *(int4*)((char*)&Ks[nb2][0] + kr0 * 256 + kcs) = pa0;
                *(int4*)((char*)&Ks[nb2][0] + (kr0 + 32) * 256 + kcs) = pa1;
                *(int4*)((char*)&Vts[nb2][0] + vr0 * 128 + vcs) = pv0;
                *(int4*)((char*)&Vts[nb2][0] + (vr0 + 64) * 128 + vcs) = pv1;
            }
            __syncthreads();
        }

        float invl = 1.0f / l_s;
        size_t orow = (size_t)(b * S_ + qg) * (NH_ * HD_) + h * HD_;
#pragma unroll
        for (int db = 0; db < 8; ++db) {
            uint2 t2;
            t2.x = cvt_pk(ot[db][0] * invl, ot[db][1] * invl);
            t2.y = cvt_pk(ot[db][2] * invl, ot[db][3] * invl);
            *(uint2*)&AO[orow + db * 16 + qd * 4] = t2;
        }
    }
}

extern "C" void kernel_launch(void* const* d_in, const int* in_sizes, int n_in,
                              void* d_out, int out_size, void* d_ws, size_t ws_size,
                              hipStream_t stream) {
    const float* x  = (const float*)d_in[0];
    const float* wq = (const float*)d_in[1];
    const float* wk = (const float*)d_in[2];
    const float* wv = (const float*)d_in[3];
    const float* wo = (const float*)d_in[4];
    float* out = (float*)d_out;

    char* p = (char*)d_ws;
    auto alloc = [&](size_t nelem) { u16* r = (u16*)p; p += nelem * 2; return r; };
    u16* xb  = alloc(4096ull * 4096);   // aliased by woT after projections
    u16* wqT = alloc(4096ull * 4096);   // aliased by Vt after projections
    u16* wkT = alloc(1024ull * 4096);   // contiguous with wvT (gemm_kv relies on it)
    u16* wvT = alloc(1024ull * 4096);
    u16* Q   = alloc(4096ull * 4096);
    u16* Kb  = alloc(4096ull * 1024);
    u16* Vb  = alloc(4096ull * 1024);
    u16* AO  = alloc(4096ull * 4096);

    dim3 tblk(64, 4);
    conv_k<<<16384, 256, 0, stream>>>(x, xb);
    tconv_k<<<dim3(64, 64), tblk, 0, stream>>>(wq, wqT, 4096, 4096);
    tconv2_k<<<dim3(16, 64, 2), tblk, 0, stream>>>(wk, wv, wkT, wvT, 4096, 1024);

    gemm256<0><<<256, 512, 0, stream>>>(xb, wqT, Q, 4096, 4096, 4096);
    gemm_kv<<<dim3(16, 32), 256, 0, stream>>>(xb, wkT, Kb, Vb, 4096, 4096);

    u16* woT = xb;
    u16* Vt  = wqT;
    tconv_k<<<dim3(64, 64), tblk, 0, stream>>>(wo, woT, 4096, 4096);

    // Q scale = 1/sqrt(128) * log2(e)  (log2-domain softmax in attn_k)
    int ng = B_ * S_ * NH_ * (HD_ / 8) + B_ * S_ * NKV_ * (HD_ / 8);
    rope_k<<<(ng + 255) / 256, 256, 0, stream>>>(Q, Kb, 0.12751743f);

    transpose_k<<<dim3(16, 32, 2), tblk, 0, stream>>>(Vb, Vt, S_, NKV_ * HD_);

    attn_k<<<dim3(S_ / 256, NH_, B_), 512, 0, stream>>>(Q, Kb, Vt, AO);

    gemm256<1><<<256, 512, 0, stream>>>(AO, woT, out, 4096, 4096, 4096);
}

// Round 5
// 724.706 us; speedup vs baseline: 1.4993x; 1.0045x over previous
//
#include <hip/hip_runtime.h>
#include <hip/hip_bf16.h>

#define B_ 2
#define S_ 2048
#define D_ 4096
#define NH_ 32
#define NKV_ 8
#define HD_ 128
#define NREP_ 4

typedef unsigned short u16;
typedef __attribute__((ext_vector_type(8))) short short8;
typedef __attribute__((ext_vector_type(4))) float f32x4;

__device__ inline float bf2f(u16 u) {
    union { unsigned u; float f; } v; v.u = ((unsigned)u) << 16; return v.f;
}
__device__ inline u16 f2bf(float f) {
    union { float f; unsigned u; } v; v.f = f;
    unsigned r = v.u + 0x7fffu + ((v.u >> 16) & 1u);
    return (u16)(r >> 16);
}
// HW packed f32x2 -> bf16x2 (RNE), one instr (T12 primitive)
__device__ inline unsigned cvt_pk(float lo, float hi) {
    unsigned r;
    asm("v_cvt_pk_bf16_f32 %0, %1, %2" : "=v"(r) : "v"(lo), "v"(hi));
    return r;
}
// v_exp_f32 = 2^x
__device__ inline float exp2_fast(float x) {
    float r;
    asm("v_exp_f32 %0, %1" : "=v"(r) : "v"(x));
    return r;
}

// async global->LDS, 16 bytes/lane (m97-verified). LDS base wave-uniform.
__device__ inline void gl_lds16(const u16* g, u16* l) {
    __builtin_amdgcn_global_load_lds(
        (const __attribute__((address_space(1))) unsigned int*)g,
        (__attribute__((address_space(3))) unsigned int*)l, 16, 0, 0);
}

// ---------------- elementwise f32 -> bf16 ----------------------------------
__global__ __launch_bounds__(256) void conv_k(const float* __restrict__ in,
                                              u16* __restrict__ out) {
    size_t i = ((size_t)blockIdx.x * 256 + threadIdx.x) * 4;
    float4 v = *(const float4*)&in[i];
    uint2 t;
    t.x = cvt_pk(v.x, v.y);
    t.y = cvt_pk(v.z, v.w);
    *(uint2*)&out[i] = t;
}

// ---------------- transpose+convert: f32 in [R][C] -> bf16 out [C][R] ------
__global__ __launch_bounds__(256) void tconv_k(const float* __restrict__ in,
                                               u16* __restrict__ out,
                                               int R, int C) {
    __shared__ u16 tile[64][65];
    int bx = blockIdx.x * 64, by = blockIdx.y * 64;
    int tx = threadIdx.x, ty = threadIdx.y;
    for (int i = ty; i < 64; i += 4)
        tile[i][tx] = f2bf(in[(size_t)(by + i) * C + bx + tx]);
    __syncthreads();
    for (int i = ty; i < 64; i += 4)
        out[(size_t)(bx + i) * R + by + tx] = tile[tx][i];
}

// z-batched variant: z=0 -> in0/out0, z=1 -> in1/out1
__global__ __launch_bounds__(256) void tconv2_k(const float* __restrict__ in0,
                                                const float* __restrict__ in1,
                                                u16* __restrict__ out0,
                                                u16* __restrict__ out1,
                                                int R, int C) {
    __shared__ u16 tile[64][65];
    const float* in = blockIdx.z ? in1 : in0;
    u16* out = blockIdx.z ? out1 : out0;
    int bx = blockIdx.x * 64, by = blockIdx.y * 64;
    int tx = threadIdx.x, ty = threadIdx.y;
    for (int i = ty; i < 64; i += 4)
        tile[i][tx] = f2bf(in[(size_t)(by + i) * C + bx + tx]);
    __syncthreads();
    for (int i = ty; i < 64; i += 4)
        out[(size_t)(bx + i) * R + by + tx] = tile[tx][i];
}

// ---------------- transpose bf16 (z-batched): in [R][C] -> out [C][R] ------
__global__ __launch_bounds__(256) void transpose_k(const u16* __restrict__ in,
                                                   u16* __restrict__ out,
                                                   int R, int C) {
    __shared__ u16 tile[64][65];
    const u16* ib = in + (size_t)blockIdx.z * R * C;
    u16* ob = out + (size_t)blockIdx.z * R * C;
    int bx = blockIdx.x * 64, by = blockIdx.y * 64;
    int tx = threadIdx.x, ty = threadIdx.y;
    for (int i = ty; i < 64; i += 4)
        tile[i][tx] = ib[(size_t)(by + i) * C + bx + tx];
    __syncthreads();
    for (int i = ty; i < 64; i += 4)
        ob[(size_t)(bx + i) * R + by + tx] = tile[tx][i];
}

// ---------------- GEMM 256^2 8-phase (m201 template, T2+T3+T4+T5) ----------
// BM=BN=256, BK=64, 512 thr (8 waves, 2Mx4N), per-wave out 128x64.
// LDS 128KB double-buffered. SWIZZLE (round-5 fix): byte ^= ((row&7)<<4) —
// XOR bits 4-6 with row bits 0-2. The old bit-5-only st_16x32 kept all 64
// lanes of a phase-read inside one 64B kk-half (16 banks -> 16-cyc floor,
// 1.26e7 conflict cycles). The 3-bit XOR spreads each 16-row fragment
// across all 8 16B-slots of the 128B row: slot = (kk*4+qd)^(ln&7) -> exactly
// 8 lanes per 4-bank group = 8-cyc wave floor, conflict-free.
// Applied BOTH sides (rule #21): inverse-swizzled global source for
// global_load_lds (linear dest) + same XOR on ds_read.

// read fragment: row in [0,256), colb = byte col in [0,128)
__device__ inline short8 lds_frag(const u16* base, int row, int colb) {
    int off = ((row >> 7) << 14) + ((row & 127) << 7) + (colb ^ ((row & 7) << 4));
    return *(const short8*)((const char*)base + off);
}

// stage one 128-row x 64-col half-tile: 2 gl_lds per wave, pre-swizzled src
__device__ inline void stage_half(const u16* g, int row0, int ldK, int k0,
                                  u16* ldsHalf, int w, int lane) {
#pragma unroll
    for (int j = 0; j < 2; ++j) {
        int Lb = (w << 11) + (j << 10) + (lane << 4);    // linear dest byte
        int r  = Lb >> 7;                                // dest row (128B rows)
        int c  = (Lb & 127) ^ ((r & 7) << 4);            // inverse-swizzled src col
        const u16* gp = g + (size_t)(row0 + r) * ldK + k0 + (c >> 1);
        gl_lds16(gp, ldsHalf + (((w << 11) + (j << 10)) >> 1));
    }
}

#define PH_MFMA(MB)                                                           \
    asm volatile("s_waitcnt lgkmcnt(0)" ::: "memory");                        \
    __builtin_amdgcn_sched_barrier(0);                                        \
    __builtin_amdgcn_s_setprio(1);                                            \
    _Pragma("unroll") for (int mi = 0; mi < 2; ++mi)                          \
      _Pragma("unroll") for (int ni = 0; ni < 4; ++ni)                        \
        _Pragma("unroll") for (int kk = 0; kk < 2; ++kk)                      \
          acc[(MB) + mi][ni] = __builtin_amdgcn_mfma_f32_16x16x32_bf16(       \
              af[mi][kk], bfr[ni][kk], acc[(MB) + mi][ni], 0, 0, 0);          \
    __builtin_amdgcn_s_setprio(0);                                            \
    __builtin_amdgcn_s_barrier();

#define TILE_BODY(T, CURA, CURB, OTHA)                                        \
  {                                                                           \
    const int t_ = (T);                                                       \
    const bool p1_ = (t_ + 1 < nt), p2_ = (t_ + 2 < nt);                      \
    short8 bfr[4][2], af[2][2];                                               \
    _Pragma("unroll") for (int ni = 0; ni < 4; ++ni)                          \
      _Pragma("unroll") for (int kk = 0; kk < 2; ++kk)                        \
        bfr[ni][kk] = lds_frag(CURB, wn * 64 + ni * 16 + ln, kk * 64 + qd * 16); \
    _Pragma("unroll") for (int mi = 0; mi < 2; ++mi)                          \
      _Pragma("unroll") for (int kk = 0; kk < 2; ++kk)                        \
        af[mi][kk] = lds_frag(CURA, wm * 128 + mi * 16 + ln, kk * 64 + qd * 16); \
    if (p1_) stage_half(Ag, 0, K, (t_ + 1) << 6, OTHA, w, lane);              \
    asm volatile("s_waitcnt lgkmcnt(8)" ::: "memory");                        \
    __builtin_amdgcn_s_barrier();                                             \
    PH_MFMA(0)                                                                \
    _Pragma("unroll") for (int mi = 0; mi < 2; ++mi)                          \
      _Pragma("unroll") for (int kk = 0; kk < 2; ++kk)                        \
        af[mi][kk] = lds_frag(CURA, wm * 128 + (mi + 2) * 16 + ln, kk * 64 + qd * 16); \
    if (p1_) stage_half(Ag, 128, K, (t_ + 1) << 6, OTHA + 8192, w, lane);     \
    __builtin_amdgcn_s_barrier();                                             \
    PH_MFMA(2)                                                                \
    _Pragma("unroll") for (int mi = 0; mi < 2; ++mi)                          \
      _Pragma("unroll") for (int kk = 0; kk < 2; ++kk)                        \
        af[mi][kk] = lds_frag(CURA, wm * 128 + (mi + 4) * 16 + ln, kk * 64 + qd * 16); \
    if (p2_) stage_half(Bg, 0, K, (t_ + 2) << 6, CURB, w, lane);              \
    __builtin_amdgcn_s_barrier();                                             \
    PH_MFMA(4)                                                                \
    _Pragma("unroll") for (int mi = 0; mi < 2; ++mi)                          \
      _Pragma("unroll") for (int kk = 0; kk < 2; ++kk)                        \
        af[mi][kk] = lds_frag(CURA, wm * 128 + (mi + 6) * 16 + ln, kk * 64 + qd * 16); \
    if (p2_) {                                                                \
        stage_half(Bg, 128, K, (t_ + 2) << 6, CURB + 8192, w, lane);          \
        asm volatile("s_waitcnt vmcnt(4)" ::: "memory");                      \
    } else if (p1_) {                                                         \
        asm volatile("s_waitcnt vmcnt(0)" ::: "memory");                      \
    }                                                                         \
    __builtin_amdgcn_s_barrier();                                             \
    PH_MFMA(6)                                                                \
  }

// OUT_MODE: 0 = bf16 C[M][N]; 1 = f32 C[M][N];
//           2 = KV split: Cv = Kb base, cols<1024 -> Kb[row][col],
//               cols>=1024 -> Vb[row][col-1024] (Vb = Kb + 4096*1024, both
//               row-stride 1024; n0 is 256-aligned so no straddle per block)
template <int OUT_MODE>
__global__ __launch_bounds__(512, 1) void gemm256(const u16* __restrict__ A,
                                                  const u16* __restrict__ Bt,
                                                  void* __restrict__ Cv,
                                                  int M, int N, int K) {
    __shared__ __align__(16) u16 As[2][16384];
    __shared__ __align__(16) u16 Bs[2][16384];

    int tid = threadIdx.x;
    int w = tid >> 6, lane = tid & 63;
    int ln = lane & 15, qd = lane >> 4;
    int wm = w >> 2, wn = w & 3;

    int nbx = N >> 8;
    int cpx = gridDim.x >> 3;                     // grid % 8 == 0 (bijective)
    int bid = blockIdx.x;
    int swz = (bid & 7) * cpx + (bid >> 3);
    int m0 = (swz / nbx) << 8;
    int n0 = (swz % nbx) << 8;

    const u16* Ag = A + (size_t)m0 * K;
    const u16* Bg = Bt + (size_t)n0 * K;
    int nt = K >> 6;

    f32x4 acc[8][4];
#pragma unroll
    for (int i = 0; i < 8; ++i)
#pragma unroll
        for (int j = 0; j < 4; ++j) acc[i][j] = f32x4{0.f, 0.f, 0.f, 0.f};

    u16* A0 = &As[0][0]; u16* A1v = &As[1][0];
    u16* B0 = &Bs[0][0]; u16* B1v = &Bs[1][0];

    stage_half(Ag, 0,   K, 0,  A0,         w, lane);
    stage_half(Ag, 128, K, 0,  A0 + 8192,  w, lane);
    stage_half(Bg, 0,   K, 0,  B0,         w, lane);
    stage_half(Bg, 128, K, 0,  B0 + 8192,  w, lane);
    stage_half(Bg, 0,   K, 64, B1v,        w, lane);
    stage_half(Bg, 128, K, 64, B1v + 8192, w, lane);
    asm volatile("s_waitcnt vmcnt(4)" ::: "memory");
    __builtin_amdgcn_s_barrier();

    for (int tt = 0; tt < nt; tt += 2) {
        TILE_BODY(tt,     A0,  B0,  A1v)
        TILE_BODY(tt + 1, A1v, B1v, A0)
    }

#pragma unroll
    for (int mi = 0; mi < 8; ++mi)
#pragma unroll
        for (int ni = 0; ni < 4; ++ni)
#pragma unroll
            for (int r = 0; r < 4; ++r) {
                int row = m0 + wm * 128 + mi * 16 + qd * 4 + r;
                int col = n0 + wn * 64 + ni * 16 + ln;
                if (OUT_MODE == 1)
                    ((float*)Cv)[(size_t)row * N + col] = acc[mi][ni][r];
                else if (OUT_MODE == 0)
                    ((u16*)Cv)[(size_t)row * N + col] = f2bf(acc[mi][ni][r]);
                else {
                    u16* dst = (u16*)Cv + ((col < 1024) ? 0 : (4096ull * 1024 - 1024));
                    dst[(size_t)row * 1024 + col] = f2bf(acc[mi][ni][r]);
                }
            }
}

// ---------------- RoPE (merged Q+K, vectorized 8 u16/thread) ---------------
// Q is scaled by 1/sqrt(128)*log2(e): scores land in log2 domain for the
// attention kernel's exp2-based softmax (exact reparametrization).
__global__ __launch_bounds__(256) void rope_k(u16* __restrict__ Q,
                                              u16* __restrict__ Kb,
                                              float qscale) {
    const int ngq = B_ * S_ * NH_ * (HD_ / 8);   // groups of 4 pairs
    const int ngk = B_ * S_ * NKV_ * (HD_ / 8);
    int i = blockIdx.x * 256 + threadIdx.x;
    u16* buf; int nheads; float scale;
    if (i < ngq) { buf = Q; nheads = NH_; scale = qscale; }
    else {
        i -= ngq;
        if (i >= ngk) return;
        buf = Kb; nheads = NKV_; scale = 1.f;
    }
    int gp = i & 15;                 // group within head (pairs 4gp..4gp+3)
    int hh = (i >> 4) % nheads;
    int row = i / (16 * nheads);
    int s = row & (S_ - 1);
    size_t base = ((size_t)row * nheads + hh) * HD_ + gp * 8;
    uint4 v = *(const uint4*)&buf[base];
    unsigned ov[4];
    unsigned* vp = (unsigned*)&v;
#pragma unroll
    for (int j = 0; j < 4; ++j) {
        int p = gp * 4 + j;
        float freq = __expf(-(float)(2 * p) * (9.210340371976184f / 128.0f));
        float ang = (float)s * freq;
        float c, sn;
        sincosf(ang, &sn, &c);
        float x0 = bf2f((u16)vp[j]), x1 = bf2f((u16)(vp[j] >> 16));
        ov[j] = cvt_pk((x0 * c - x1 * sn) * scale, (x0 * sn + x1 * c) * scale);
    }
    *(uint4*)&buf[base] = *(uint4*)ov;
}

// ---------------- flash attention (transposed-S, log2-domain softmax) ------
// grid (S/256, NH, B), 512 threads (8 waves); block does qt=bx and qt=15-bx
// (constant 34 key-tiles). LDS 64KB exactly (unpadded + XOR swizzle) so TWO
// blocks co-reside per CU.
__global__ __launch_bounds__(512, 4) void attn_k(const u16* __restrict__ Q,
                                                 const u16* __restrict__ K,
                                                 const u16* __restrict__ Vt,
                                                 u16* __restrict__ AO) {
    __shared__ __align__(16) u16 Ks[2][64 * 128];    // [sk][d] swizzled, 16KB/buf
    __shared__ __align__(16) u16 Vts[2][128 * 64];   // [d][sk] swizzled, 16KB/buf

    int tid = threadIdx.x;
    int w = tid >> 6, lane = tid & 63;
    int ln = lane & 15, qd = lane >> 4;
    int sw = (ln & 7) << 4;          // read-side XOR (row&7 == ln&7)

    int h  = blockIdx.y;
    int b  = blockIdx.z;
    int g  = h >> 2;

    const u16* Kbase = K + (size_t)(b * S_) * (NKV_ * HD_) + g * HD_;
    const u16* Vtb   = Vt + ((size_t)(b * NKV_ + g)) * HD_ * S_;

    // staging map: K rows kr0,kr0+32 (col 16B x (tid&15)); V rows vr0,vr0+64
    int kr0 = tid >> 4;
    int kg0 = (tid & 15) * 8;                       // u16 col (global)
    int kcs = (kg0 * 2) ^ ((kr0 & 7) << 4);         // swizzled LDS byte col
    int vr0 = tid >> 3;
    int vg0 = (tid & 7) * 8;
    int vcs = (vg0 * 2) ^ ((vr0 & 7) << 4);

    for (int pass = 0; pass < 2; ++pass) {
        int qt = pass ? (S_ / 128 - 1 - (int)blockIdx.x) : (int)blockIdx.x;
        int q0 = qt * 128;
        int qb = q0 + w * 16;            // wave q base
        int qg = qb + ln;                // lane's q row
        int ntw   = ((qb + 15) >> 6) + 1;  // active tiles for this wave
        int nfull = (qb + 1) >> 6;         // fully-unmasked tiles

        const u16* qptr = Q + ((size_t)(b * S_ + qg)) * (NH_ * HD_) + h * HD_;
        short8 bq[4];
#pragma unroll
        for (int kq = 0; kq < 4; ++kq)
            bq[kq] = *(const short8*)(qptr + kq * 32 + qd * 8);

        f32x4 ot[8];
#pragma unroll
        for (int db = 0; db < 8; ++db) ot[db] = f32x4{0.f, 0.f, 0.f, 0.f};
        float m_s = -1e30f, l_s = 0.f;

        int nk = 2 * qt + 2;

        {
            int4 a0 = *(const int4*)(Kbase + (size_t)kr0 * (NKV_ * HD_) + kg0);
            int4 a1 = *(const int4*)(Kbase + (size_t)(kr0 + 32) * (NKV_ * HD_) + kg0);
            int4 v0 = *(const int4*)(Vtb + (size_t)vr0 * S_ + vg0);
            int4 v1 = *(const int4*)(Vtb + (size_t)(vr0 + 64) * S_ + vg0);
            *(int4*)((char*)&Ks[0][0] + kr0 * 256 + kcs) = a0;
            *(int4*)((char*)&Ks[0][0] + (kr0 + 32) * 256 + kcs) = a1;
            *(int4*)((char*)&Vts[0][0] + vr0 * 128 + vcs) = v0;
            *(int4*)((char*)&Vts[0][0] + (vr0 + 64) * 128 + vcs) = v1;
        }
        __syncthreads();

        for (int kt = 0; kt < nk; ++kt) {
            int bb = kt & 1;
            int k0 = kt * 64;
            bool pf = (kt + 1 < nk);
            int4 pa0, pa1, pv0, pv1;
            if (pf) {
                int k0n = k0 + 64;
                pa0 = *(const int4*)(Kbase + (size_t)(k0n + kr0) * (NKV_ * HD_) + kg0);
                pa1 = *(const int4*)(Kbase + (size_t)(k0n + kr0 + 32) * (NKV_ * HD_) + kg0);
                pv0 = *(const int4*)(Vtb + (size_t)vr0 * S_ + k0n + vg0);
                pv1 = *(const int4*)(Vtb + (size_t)(vr0 + 64) * S_ + k0n + vg0);
            }

            if (kt < ntw) {
                // S^T = K Q^T
                f32x4 st[4];
#pragma unroll
                for (int kb = 0; kb < 4; ++kb) st[kb] = f32x4{0.f, 0.f, 0.f, 0.f};
                __builtin_amdgcn_s_setprio(1);
#pragma unroll
                for (int kb = 0; kb < 4; ++kb)
#pragma unroll
                    for (int kq = 0; kq < 4; ++kq) {
                        short8 ak = *(const short8*)((const char*)&Ks[bb][0] +
                                    (kb * 16 + ln) * 256 + ((kq * 64 + qd * 16) ^ sw));
                        st[kb] = __builtin_amdgcn_mfma_f32_16x16x32_bf16(ak, bq[kq], st[kb], 0, 0, 0);
                    }
                __builtin_amdgcn_s_setprio(0);

                float mx;
                if (kt >= nfull) {          // diagonal tile: mask + max
                    int lim = qg - k0 - qd * 4;   // masked iff 16*kb + r > lim
                    mx = -1e30f;
#pragma unroll
                    for (int kb = 0; kb < 4; ++kb)
#pragma unroll
                        for (int r = 0; r < 4; ++r) {
                            if (16 * kb + r > lim) st[kb][r] = -1e30f;
                            mx = fmaxf(mx, st[kb][r]);
                        }
                } else {                    // full tile: max only
                    mx = st[0][0];
#pragma unroll
                    for (int kb = 0; kb < 4; ++kb)
#pragma unroll
                        for (int r = 0; r < 4; ++r)
                            if (kb + r) mx = fmaxf(mx, st[kb][r]);
                }
                mx = fmaxf(mx, __shfl_xor(mx, 16, 64));
                mx = fmaxf(mx, __shfl_xor(mx, 32, 64));

                // T13 defer-max: only rescale when the max grew by > 8 (log2)
                if (__any(mx > m_s + 8.f)) {
                    float mn = fmaxf(m_s, mx);
                    float alpha = exp2_fast(m_s - mn);
                    m_s = mn;
                    l_s *= alpha;
#pragma unroll
                    for (int db = 0; db < 8; ++db)
#pragma unroll
                        for (int r = 0; r < 4; ++r) ot[db][r] *= alpha;
                }
                float rs = 0.f;
#pragma unroll
                for (int kb = 0; kb < 4; ++kb)
#pragma unroll
                    for (int r = 0; r < 4; ++r) {
                        float pv = exp2_fast(st[kb][r] - m_s);
                        st[kb][r] = pv;
                        rs += pv;
                    }
                rs += __shfl_xor(rs, 16, 64);
                rs += __shfl_xor(rs, 32, 64);
                l_s += rs;

                unsigned pk[4][2];
#pragma unroll
                for (int kb = 0; kb < 4; ++kb) {
                    pk[kb][0] = cvt_pk(st[kb][0], st[kb][1]);
                    pk[kb][1] = cvt_pk(st[kb][2], st[kb][3]);
                }
                int sA = ((qd & 1) << 5) + ln;
                int sB = sA + 16;
                bool hi = (qd & 2) != 0;
#pragma unroll
                for (int ks = 0; ks < 2; ++ks) {
                    unsigned t0a = (unsigned)__shfl((int)pk[2 * ks][0], sA, 64);
                    unsigned t0b = (unsigned)__shfl((int)pk[2 * ks][1], sA, 64);
                    unsigned t1a = (unsigned)__shfl((int)pk[2 * ks + 1][0], sA, 64);
                    unsigned t1b = (unsigned)__shfl((int)pk[2 * ks + 1][1], sA, 64);
                    unsigned t2a = (unsigned)__shfl((int)pk[2 * ks][0], sB, 64);
                    unsigned t2b = (unsigned)__shfl((int)pk[2 * ks][1], sB, 64);
                    unsigned t3a = (unsigned)__shfl((int)pk[2 * ks + 1][0], sB, 64);
                    unsigned t3b = (unsigned)__shfl((int)pk[2 * ks + 1][1], sB, 64);
                    union { unsigned u[4]; short8 s8; } bp;
                    bp.u[0] = hi ? t1a : t0a;
                    bp.u[1] = hi ? t1b : t0b;
                    bp.u[2] = hi ? t3a : t2a;
                    bp.u[3] = hi ? t3b : t2b;
                    __builtin_amdgcn_s_setprio(1);
#pragma unroll
                    for (int db = 0; db < 8; ++db) {
                        short8 av = *(const short8*)((const char*)&Vts[bb][0] +
                                    (db * 16 + ln) * 128 + ((ks * 64 + qd * 16) ^ sw));
                        ot[db] = __builtin_amdgcn_mfma_f32_16x16x32_bf16(av, bp.s8, ot[db], 0, 0, 0);
                    }
                    __builtin_amdgcn_s_setprio(0);
                }
            }

            if (pf) {
                int nb2 = bb ^ 1;
                *(int4*)((char*)&Ks[nb2][0] + kr0 * 256 + kcs) = pa0;
                *(int4*)((char*)&Ks[nb2][0] + (kr0 + 32) * 256 + kcs) = pa1;
                *(int4*)((char*)&Vts[nb2][0] + vr0 * 128 + vcs) = pv0;
                *(int4*)((char*)&Vts[nb2][0] + (vr0 + 64) * 128 + vcs) = pv1;
            }
            __syncthreads();
        }

        float invl = 1.0f / l_s;
        size_t orow = (size_t)(b * S_ + qg) * (NH_ * HD_) + h * HD_;
#pragma unroll
        for (int db = 0; db < 8; ++db) {
            uint2 t2;
            t2.x = cvt_pk(ot[db][0] * invl, ot[db][1] * invl);
            t2.y = cvt_pk(ot[db][2] * invl, ot[db][3] * invl);
            *(uint2*)&AO[orow + db * 16 + qd * 4] = t2;
        }
    }
}

extern "C" void kernel_launch(void* const* d_in, const int* in_sizes, int n_in,
                              void* d_out, int out_size, void* d_ws, size_t ws_size,
                              hipStream_t stream) {
    const float* x  = (const float*)d_in[0];
    const float* wq = (const float*)d_in[1];
    const float* wk = (const float*)d_in[2];
    const float* wv = (const float*)d_in[3];
    const float* wo = (const float*)d_in[4];
    float* out = (float*)d_out;

    char* p = (char*)d_ws;
    auto alloc = [&](size_t nelem) { u16* r = (u16*)p; p += nelem * 2; return r; };
    u16* xb  = alloc(4096ull * 4096);   // aliased by woT after projections
    u16* wqT = alloc(4096ull * 4096);   // aliased by Vt after projections
    u16* wkT = alloc(1024ull * 4096);   // contiguous with wvT (merged KV GEMM)
    u16* wvT = alloc(1024ull * 4096);
    u16* Q   = alloc(4096ull * 4096);
    u16* Kb  = alloc(4096ull * 1024);   // contiguous with Vb (gemm256<2> relies on it)
    u16* Vb  = alloc(4096ull * 1024);
    u16* AO  = alloc(4096ull * 4096);

    dim3 tblk(64, 4);
    conv_k<<<16384, 256, 0, stream>>>(x, xb);
    tconv_k<<<dim3(64, 64), tblk, 0, stream>>>(wq, wqT, 4096, 4096);
    tconv2_k<<<dim3(16, 64, 2), tblk, 0, stream>>>(wk, wv, wkT, wvT, 4096, 1024);

    gemm256<0><<<256, 512, 0, stream>>>(xb, wqT, Q, 4096, 4096, 4096);
    gemm256<2><<<128, 512, 0, stream>>>(xb, wkT, Kb, 4096, 2048, 4096);

    u16* woT = xb;
    u16* Vt  = wqT;
    tconv_k<<<dim3(64, 64), tblk, 0, stream>>>(wo, woT, 4096, 4096);

    // Q scale = 1/sqrt(128) * log2(e)  (log2-domain softmax in attn_k)
    int ng = B_ * S_ * NH_ * (HD_ / 8) + B_ * S_ * NKV_ * (HD_ / 8);
    rope_k<<<(ng + 255) / 256, 256, 0, stream>>>(Q, Kb, 0.12751743f);

    transpose_k<<<dim3(16, 32, 2), tblk, 0, stream>>>(Vb, Vt, S_, NKV_ * HD_);

    attn_k<<<dim3(S_ / 256, NH_, B_), 512, 0, stream>>>(Q, Kb, Vt, AO);

    gemm256<1><<<256, 512, 0, stream>>>(AO, woT, out, 4096, 4096, 4096);
}